// Round 8
// baseline (7329.808 us; speedup 1.0000x reference)
//
#include <hip/hip_runtime.h>

#define BB 4
#define HH 20
#define DHD 64
#define DD 1280
#define DFFN 5120
#define VV 8000
#define HIST 1024
#define TENC 512
#define KVLEN 1025
#define NLAYER 16

static const size_t NK_OFF = 0;
static const size_t NV_OFF = 83968000ull;   // 16*4*20*64*1025
static const size_t LG_OFF = 167936000ull;
static const size_t KV_IDX = 167968000ull;

struct Prm {
    const float *kc, *vc, *ck, *cv;
    const int* ids;
    const float *mflag, *emb, *pe, *snw, *snb, *wq, *bq, *wk, *wv, *bv;
    const float *fcw, *fcb, *cnw, *cnb, *cwq, *cbq, *cfcw, *cfcb, *mnw, *mnb;
    const float *w1, *b1, *w2, *b2, *lnow, *lnob, *projw, *projb;
    float* out;
    float* ws;
    unsigned* bar;
};

__device__ __forceinline__ void fma4(float4& a, float s, const float4& w) {
    a.x += s * w.x; a.y += s * w.y; a.z += s * w.z; a.w += s * w.w;
}

// monotonic grid barrier with exponential-backoff polling.
// device-scope fences handle cross-XCD L2 non-coherence.
__device__ __forceinline__ void gsync(unsigned* bar, unsigned& tgt) {
    __syncthreads();
    if (threadIdx.x == 0) {
        __threadfence();   // release: L2 writeback, device visibility
        unsigned old = __hip_atomic_fetch_add(bar, 1u, __ATOMIC_RELAXED, __HIP_MEMORY_SCOPE_AGENT);
        if (old != tgt - 1u) {   // last arriver skips polling
            int slp = 1, polls = 0;
            while (__hip_atomic_load(bar, __ATOMIC_RELAXED, __HIP_MEMORY_SCOPE_AGENT) < tgt) {
                for (int s = 0; s < slp; ++s) __builtin_amdgcn_s_sleep(8);  // 512 cyc each
                if (slp < 16) slp <<= 1;           // cap ~8192 cyc ≈ 3.4 µs
                if (++polls > (1 << 16)) break;    // bounded: degrade, never hang
            }
        }
        __threadfence();   // acquire: invalidate stale cached lines
    }
    __syncthreads();
    tgt += gridDim.x;
}

__device__ __forceinline__ float blk_red_sum(float v, float* r4) {
#pragma unroll
    for (int o = 32; o; o >>= 1) v += __shfl_xor(v, o, 64);
    int w = threadIdx.x >> 6;
    __syncthreads();
    if ((threadIdx.x & 63) == 0) r4[w] = v;
    __syncthreads();
    return r4[0] + r4[1] + r4[2] + r4[3];
}

// x[b] += rbias + sum_j pin[j][b]; write x; xn[b] = LN(x)*lw+lb.  (block handles batch b)
__device__ void ln_micro(int b, float* x, const float* rbias, const float* pin, int np,
                         const float* lw, const float* lb, float* xn, float* r4) {
    int tid = threadIdx.x;
    float vloc[5]; float s = 0.f;
#pragma unroll
    for (int e = 0; e < 5; ++e) {
        int d = e * 256 + tid;
        float v = x[b * DD + d] + rbias[d];
        for (int j = 0; j < np; ++j) v += pin[(size_t)(j * BB + b) * DD + d];
        vloc[e] = v; s += v;
    }
#pragma unroll
    for (int e = 0; e < 5; ++e) x[b * DD + e * 256 + tid] = vloc[e];
    s = blk_red_sum(s, r4);
    float mean = s * (1.0f / DD);
    float sq = 0.f;
#pragma unroll
    for (int e = 0; e < 5; ++e) { float d0 = vloc[e] - mean; sq += d0 * d0; }
    sq = blk_red_sum(sq, r4);
    float rstd = rsqrtf(sq * (1.0f / DD) + 1e-5f);
#pragma unroll
    for (int e = 0; e < 5; ++e) {
        int d = e * 256 + tid;
        xn[b * DD + d] = (vloc[e] - mean) * rstd * lw[d] + lb[d];
    }
}

// GEMV core: acts am[4][rows] (LDS), W tile rows x 64 cols; writes outp[b*outN + col0 + c].
__device__ __forceinline__ void gemv_core(const float* Wt, int ldw, int rows,
                                          const float* am, float* red,
                                          float* outp, int outN, int col0) {
    int tid = threadIdx.x, cl = tid & 15, sg = tid >> 4;
    float4 a0{0,0,0,0}, a1{0,0,0,0}, a2{0,0,0,0}, a3{0,0,0,0};
    const float* Wp = Wt + cl * 4;
    int iters = rows >> 4;
#pragma unroll 4
    for (int it = 0; it < iters; ++it) {
        int r = sg + it * 16;
        float4 w4 = *(const float4*)(Wp + (size_t)r * ldw);
        fma4(a0, am[r], w4);            fma4(a1, am[rows + r], w4);
        fma4(a2, am[2 * rows + r], w4); fma4(a3, am[3 * rows + r], w4);
    }
    int cq = cl * 4;
    float* rg = red + (size_t)(sg * 4) * 64;
    rg[cq] = a0.x; rg[cq+1] = a0.y; rg[cq+2] = a0.z; rg[cq+3] = a0.w;
    rg += 64; rg[cq] = a1.x; rg[cq+1] = a1.y; rg[cq+2] = a1.z; rg[cq+3] = a1.w;
    rg += 64; rg[cq] = a2.x; rg[cq+1] = a2.y; rg[cq+2] = a2.z; rg[cq+3] = a2.w;
    rg += 64; rg[cq] = a3.x; rg[cq+1] = a3.y; rg[cq+2] = a3.z; rg[cq+3] = a3.w;
    __syncthreads();
    int b = tid >> 6, c = tid & 63;
    float v = 0.f;
#pragma unroll
    for (int g = 0; g < 16; ++g) v += red[(size_t)(g * 4 + b) * 64 + c];
    outp[(size_t)b * outN + col0 + c] = v;
}

__global__ void bar_init(unsigned* bar) { *bar = 0u; }

__global__ __launch_bounds__(256, 3) void mega(Prm p) {
    __shared__ float sm[5376];        // 21.5 KB: red[4096] | am[1280]
    float* red = sm;
    float* am  = sm + 4096;
    // attention aliases (inside red region; phases barrier-separated)
    float* qs    = sm;          // 64
    float* knS   = sm + 64;     // 64
    float* vnS   = sm + 128;    // 64
    float* sc8   = sm + 192;    // [8][128]
    float* parr  = sm + 1216;   // 128
    float* redA  = sm + 1344;   // 128
    float* pvred = sm + 1472;   // [16][64]
    float* snS   = sm + 2496;   // 1

    const int bid = blockIdx.x, tid = threadIdx.x;
    const int G = gridDim.x;
    unsigned tgt = G;

    float* x      = p.ws + 64;
    float* xn     = p.ws + 5184;
    float* qkvp   = p.ws + 10304;    // [24][20][4][64] = 122880
    float* selfS  = p.ws + 133184;   // [4*20*8]*66 = 42240
    float* crossS = p.ws + 175424;   // [4*20*4]*66 = 21120
    float* fcP    = p.ws + 196544;   // [16*4][1280] = 81920
    float* cfcP   = p.ws + 278464;   // 81920
    float* f1P    = p.ws + 360384;   // [8*4][5120] = 163840
    float* ff2P   = p.ws + 524224;   // [16*4][1280] = 81920
    float* projP  = p.ws + 606144;   // [4*4][8000] = 128000

    float* nk = p.out + NK_OFF;
    float* nv = p.out + NV_OFF;
    const float flag = p.mflag[0];

    // ---- P0: embed + LN0 ----
    if (bid < BB) {
        int b = bid, tok = p.ids[b];
        float vloc[5]; float s = 0.f;
#pragma unroll
        for (int e = 0; e < 5; ++e) {
            int d = e * 256 + tid;
            float v = p.emb[(size_t)tok * DD + d] + p.pe[(size_t)HIST * DD + d];
            vloc[e] = v; s += v;
            x[b * DD + d] = v;
        }
        s = blk_red_sum(s, sm);
        float mean = s * (1.0f / DD);
        float sq = 0.f;
#pragma unroll
        for (int e = 0; e < 5; ++e) { float d0 = vloc[e] - mean; sq += d0 * d0; }
        sq = blk_red_sum(sq, sm);
        float rstd = rsqrtf(sq * (1.0f / DD) + 1e-5f);
#pragma unroll
        for (int e = 0; e < 5; ++e) {
            int d = e * 256 + tid;
            xn[b * DD + d] = (vloc[e] - mean) * rstd * p.snw[d] + p.snb[d];
        }
    }
    gsync(p.bar, tgt);

    for (int l = 0; l < NLAYER; ++l) {
        const float* kc_l  = p.kc  + (size_t)l * 5242880;
        const float* vc_l  = p.vc  + (size_t)l * 5242880;
        const float* ck_l  = p.ck  + (size_t)l * 2621440;
        const float* cv_l  = p.cv  + (size_t)l * 2621440;
        float* nk_l = nk + (size_t)l * 5248000;
        float* nv_l = nv + (size_t)l * 5248000;
        const float* wq_l   = p.wq   + (size_t)l * 1638400;
        const float* wk_l   = p.wk   + (size_t)l * 1638400;
        const float* wv_l   = p.wv   + (size_t)l * 1638400;
        const float* cwq_l  = p.cwq  + (size_t)l * 1638400;
        const float* fcw_l  = p.fcw  + (size_t)l * 1638400;
        const float* cfcw_l = p.cfcw + (size_t)l * 1638400;
        const float* bq_l   = p.bq   + (size_t)l * 1280;
        const float* bv_l   = p.bv   + (size_t)l * 1280;
        const float* cbq_l  = p.cbq  + (size_t)l * 1280;
        const float* fcb_l  = p.fcb  + (size_t)l * DD;
        const float* cfcb_l = p.cfcb + (size_t)l * DD;
        const float* w1_l   = p.w1   + (size_t)l * 6553600;
        const float* b1_l   = p.b1   + (size_t)l * DFFN;
        const float* w2_l   = p.w2   + (size_t)l * 6553600;
        const float* b2_l   = p.b2   + (size_t)l * DD;

        // ---- P1: self QKV, 480 units = (mat*20+h)*8 + rc, rows=160 ----
        for (int u = bid; u < 480; u += G) {
            int rc = u & 7, mh = u >> 3, h = mh % 20, mat = mh / 20;
            const float* W = (mat == 0 ? wq_l : mat == 1 ? wk_l : wv_l)
                           + (size_t)h * 81920 + (size_t)rc * 160 * 64;
            for (int i = tid; i < 640; i += 256)
                am[i] = xn[(i / 160) * DD + rc * 160 + (i % 160)];
            __syncthreads();
            gemv_core(W, 64, 160, am, red,
                      qkvp + (size_t)((mat * 8 + rc) * HH + h) * BB * 64, 64, 0);
            __syncthreads();
        }
        gsync(p.bar, tgt);

        // ---- P2: self-attention, 640 units = ((h*4+b)*8)+c, chunk=128 ----
        for (int u = bid; u < 640; u += G) {
            int c = u & 7, hb = u >> 3, b = hb & 3, h = hb >> 2;
            if (tid < 64) {
                float qv = bq_l[h * 64 + tid];
#pragma unroll
                for (int j = 0; j < 8; ++j)
                    qv += qkvp[(size_t)((j * HH + h) * BB + b) * 64 + tid];
                qs[tid] = qv;
            } else if (tid < 128 && c == 0) {
                int t2 = tid - 64;
                float kn = 0.f;
#pragma unroll
                for (int j = 0; j < 8; ++j)
                    kn += qkvp[(size_t)(((8 + j) * HH + h) * BB + b) * 64 + t2];
                knS[t2] = kn;
                nk_l[((size_t)(b * HH + h) * 64 + t2) * KVLEN + HIST] = kn;
            } else if (tid < 192 && c == 0) {
                int t2 = tid - 128;
                float vn = bv_l[h * 64 + t2];
#pragma unroll
                for (int j = 0; j < 8; ++j)
                    vn += qkvp[(size_t)(((16 + j) * HH + h) * BB + b) * 64 + t2];
                vnS[t2] = vn;
                nv_l[(size_t)(b * HH + h) * KVLEN * 64 + (size_t)HIST * 64 + t2] = vn;
            }
            __syncthreads();
            // K phase
            int clK = tid & 31, gK = tid >> 5;
            int jb = c * 128 + clK * 4;
            const float* kb = kc_l + (size_t)(b * HH + h) * 64 * HIST;
            float* nkb = nk_l + (size_t)(b * HH + h) * 64 * KVLEN;
            float ax = 0, ay = 0, az = 0, aw = 0;
#pragma unroll
            for (int it = 0; it < 8; ++it) {
                int dh = gK * 8 + it;
                float4 k4 = *(const float4*)(kb + (size_t)dh * HIST + jb);
                float* nr = nkb + (size_t)dh * KVLEN + jb;
                nr[0] = k4.x; nr[1] = k4.y; nr[2] = k4.z; nr[3] = k4.w;
                float qd = qs[dh];
                ax += qd * k4.x; ay += qd * k4.y; az += qd * k4.z; aw += qd * k4.w;
            }
            sc8[gK * 128 + clK * 4 + 0] = ax; sc8[gK * 128 + clK * 4 + 1] = ay;
            sc8[gK * 128 + clK * 4 + 2] = az; sc8[gK * 128 + clK * 4 + 3] = aw;
            __syncthreads();
            float s = 0.f;
            if (tid < 128) {
#pragma unroll
                for (int g = 0; g < 8; ++g) s += sc8[g * 128 + tid];
                int j = c * 128 + tid;
                if (j != 0) s += -128.0f * flag;
            }
            if (c == 0 && tid < 64) {
                float pp = qs[tid] * knS[tid];
#pragma unroll
                for (int o = 32; o; o >>= 1) pp += __shfl_xor(pp, o, 64);
                if (tid == 0) snS[0] = pp + (-128.0f * flag);
            }
            if (tid < 128) redA[tid] = s;
            __syncthreads();
            for (int st = 64; st; st >>= 1) {
                if (tid < st) redA[tid] = fmaxf(redA[tid], redA[tid + st]);
                __syncthreads();
            }
            float m = redA[0];
            if (c == 0) m = fmaxf(m, snS[0]);
            __syncthreads();
            float pp = 0.f;
            if (tid < 128) { pp = expf(s - m); parr[tid] = pp; redA[tid] = pp; }
            __syncthreads();
            for (int st = 64; st; st >>= 1) {
                if (tid < st) redA[tid] += redA[tid + st];
                __syncthreads();
            }
            float ssum = redA[0];
            float en = (c == 0) ? expf(snS[0] - m) : 0.0f;
            // V phase
            int clV = tid & 15, rg = tid >> 4;
            const float* vb = vc_l + (size_t)(b * HH + h) * HIST * 64;
            float* nvb = nv_l + (size_t)(b * HH + h) * KVLEN * 64;
            float vx = 0, vy = 0, vz = 0, vw = 0;
#pragma unroll
            for (int it = 0; it < 8; ++it) {
                int i = rg * 8 + it;
                size_t jj = (size_t)(c * 128 + i);
                float4 v4 = *(const float4*)(vb + jj * 64 + clV * 4);
                *(float4*)(nvb + jj * 64 + clV * 4) = v4;
                float pw = parr[i];
                vx += pw * v4.x; vy += pw * v4.y; vz += pw * v4.z; vw += pw * v4.w;
            }
            pvred[rg * 64 + clV * 4 + 0] = vx; pvred[rg * 64 + clV * 4 + 1] = vy;
            pvred[rg * 64 + clV * 4 + 2] = vz; pvred[rg * 64 + clV * 4 + 3] = vw;
            __syncthreads();
            float* st_ = selfS + (size_t)((b * HH + h) * 8 + c) * 66;
            if (tid == 0) { st_[0] = m; st_[1] = ssum + en; }
            if (tid < 64) {
                float pv = 0.f;
#pragma unroll
                for (int rgi = 0; rgi < 16; ++rgi) pv += pvred[rgi * 64 + tid];
                if (c == 0) pv += en * vnS[tid];
                st_[2 + tid] = pv;
            }
            __syncthreads();
        }
        gsync(p.bar, tgt);

        // ---- P3: fc out-proj, 320 units = rc*20+cc, rows=80, merge selfS(8) ----
        for (int u = bid; u < 320; u += G) {
            int cc = u % 20, rcx = u / 20, row0 = rcx * 80;
            for (int i = tid; i < 320; i += 256) {
                int b = i / 80, r = i % 80, gr = row0 + r, hh = gr >> 6, dh = gr & 63;
                const float* st = selfS + (size_t)((b * HH + hh) * 8) * 66;
                float M = st[0];
#pragma unroll
                for (int ci = 1; ci < 8; ++ci) M = fmaxf(M, st[ci * 66]);
                float den = 0.f, num = 0.f;
#pragma unroll
                for (int ci = 0; ci < 8; ++ci) {
                    float e = expf(st[ci * 66] - M);
                    den += e * st[ci * 66 + 1];
                    num += e * st[ci * 66 + 2 + dh];
                }
                am[b * 80 + r] = num / den;
            }
            __syncthreads();
            gemv_core(fcw_l + (size_t)row0 * DD + cc * 64, DD, 80, am, red,
                      fcP + (size_t)(rcx * BB) * DD, DD, cc * 64);
            __syncthreads();
        }
        gsync(p.bar, tgt);

        // ---- P4: LN1 ----
        if (bid < BB) ln_micro(bid, x, fcb_l, fcP, 16, p.cnw + l * DD, p.cnb + l * DD, xn, sm);
        gsync(p.bar, tgt);

        // ---- P5: cross Q, 160 units = h*8+rc, rows=160 ----
        for (int u = bid; u < 160; u += G) {
            int rc = u & 7, h = u >> 3;
            const float* W = cwq_l + (size_t)h * 81920 + (size_t)rc * 160 * 64;
            for (int i = tid; i < 640; i += 256)
                am[i] = xn[(i / 160) * DD + rc * 160 + (i % 160)];
            __syncthreads();
            gemv_core(W, 64, 160, am, red,
                      qkvp + (size_t)(rc * HH + h) * BB * 64, 64, 0);
            __syncthreads();
        }
        gsync(p.bar, tgt);

        // ---- P6: cross-attention, 320 units = ((h*4+b)*4)+c, chunk=128 ----
        for (int u = bid; u < 320; u += G) {
            int c = u & 3, hb = u >> 2, b = hb & 3, h = hb >> 2;
            if (tid < 64) {
                float qv = cbq_l[h * 64 + tid];
#pragma unroll
                for (int j = 0; j < 8; ++j)
                    qv += qkvp[(size_t)((j * HH + h) * BB + b) * 64 + tid];
                qs[tid] = qv;
            }
            __syncthreads();
            int clK = tid & 31, gK = tid >> 5;
            int jb = c * 128 + clK * 4;
            const float* kb = ck_l + (size_t)(b * HH + h) * 64 * TENC;
            float ax = 0, ay = 0, az = 0, aw = 0;
#pragma unroll
            for (int it = 0; it < 8; ++it) {
                int dh = gK * 8 + it;
                float4 k4 = *(const float4*)(kb + (size_t)dh * TENC + jb);
                float qd = qs[dh];
                ax += qd * k4.x; ay += qd * k4.y; az += qd * k4.z; aw += qd * k4.w;
            }
            sc8[gK * 128 + clK * 4 + 0] = ax; sc8[gK * 128 + clK * 4 + 1] = ay;
            sc8[gK * 128 + clK * 4 + 2] = az; sc8[gK * 128 + clK * 4 + 3] = aw;
            __syncthreads();
            float s = 0.f;
            if (tid < 128) {
#pragma unroll
                for (int g = 0; g < 8; ++g) s += sc8[g * 128 + tid];
            }
            if (tid < 128) redA[tid] = s;
            __syncthreads();
            for (int st = 64; st; st >>= 1) {
                if (tid < st) redA[tid] = fmaxf(redA[tid], redA[tid + st]);
                __syncthreads();
            }
            float m = redA[0];
            __syncthreads();
            float pp = 0.f;
            if (tid < 128) { pp = expf(s - m); parr[tid] = pp; redA[tid] = pp; }
            __syncthreads();
            for (int st = 64; st; st >>= 1) {
                if (tid < st) redA[tid] += redA[tid + st];
                __syncthreads();
            }
            float ssum = redA[0];
            int clV = tid & 15, rg = tid >> 4;
            const float* vb = cv_l + (size_t)(b * HH + h) * TENC * 64;
            float vx = 0, vy = 0, vz = 0, vw = 0;
#pragma unroll
            for (int it = 0; it < 8; ++it) {
                int i = rg * 8 + it;
                size_t jj = (size_t)(c * 128 + i);
                float4 v4 = *(const float4*)(vb + jj * 64 + clV * 4);
                float pw = parr[i];
                vx += pw * v4.x; vy += pw * v4.y; vz += pw * v4.z; vw += pw * v4.w;
            }
            pvred[rg * 64 + clV * 4 + 0] = vx; pvred[rg * 64 + clV * 4 + 1] = vy;
            pvred[rg * 64 + clV * 4 + 2] = vz; pvred[rg * 64 + clV * 4 + 3] = vw;
            __syncthreads();
            float* st_ = crossS + (size_t)((b * HH + h) * 4 + c) * 66;
            if (tid == 0) { st_[0] = m; st_[1] = ssum; }
            if (tid < 64) {
                float pv = 0.f;
#pragma unroll
                for (int rgi = 0; rgi < 16; ++rgi) pv += pvred[rgi * 64 + tid];
                st_[2 + tid] = pv;
            }
            __syncthreads();
        }
        gsync(p.bar, tgt);

        // ---- P7: cfc out-proj, 320 units, merge crossS(4) ----
        for (int u = bid; u < 320; u += G) {
            int cc = u % 20, rcx = u / 20, row0 = rcx * 80;
            for (int i = tid; i < 320; i += 256) {
                int b = i / 80, r = i % 80, gr = row0 + r, hh = gr >> 6, dh = gr & 63;
                const float* st = crossS + (size_t)((b * HH + hh) * 4) * 66;
                float M = st[0];
#pragma unroll
                for (int ci = 1; ci < 4; ++ci) M = fmaxf(M, st[ci * 66]);
                float den = 0.f, num = 0.f;
#pragma unroll
                for (int ci = 0; ci < 4; ++ci) {
                    float e = expf(st[ci * 66] - M);
                    den += e * st[ci * 66 + 1];
                    num += e * st[ci * 66 + 2 + dh];
                }
                am[b * 80 + r] = num / den;
            }
            __syncthreads();
            gemv_core(cfcw_l + (size_t)row0 * DD + cc * 64, DD, 80, am, red,
                      cfcP + (size_t)(rcx * BB) * DD, DD, cc * 64);
            __syncthreads();
        }
        gsync(p.bar, tgt);

        // ---- P8: LN2 ----
        if (bid < BB) ln_micro(bid, x, cfcb_l, cfcP, 16, p.mnw + l * DD, p.mnb + l * DD, xn, sm);
        gsync(p.bar, tgt);

        // ---- P9: FFN1, 640 units = rc*80+cc, rows=160 ----
        for (int u = bid; u < 640; u += G) {
            int cc = u % 80, rcx = u / 80, row0 = rcx * 160;
            for (int i = tid; i < 640; i += 256)
                am[i] = xn[(i / 160) * DD + row0 + (i % 160)];
            __syncthreads();
            gemv_core(w1_l + (size_t)row0 * DFFN + cc * 64, DFFN, 160, am, red,
                      f1P + (size_t)(rcx * BB) * DFFN, DFFN, cc * 64);
            __syncthreads();
        }
        gsync(p.bar, tgt);

        // ---- P10: FFN2, 320 units = rc*20+cc, rows=320, relu-merge f1P(8) ----
        for (int u = bid; u < 320; u += G) {
            int cc = u % 20, rcx = u / 20, row0 = rcx * 320;
            for (int i = tid; i < 1280; i += 256) {
                int b = i / 320, r = i % 320;
                float v = b1_l[row0 + r];
#pragma unroll
                for (int j = 0; j < 8; ++j)
                    v += f1P[(size_t)(j * BB + b) * DFFN + row0 + r];
                am[i] = fmaxf(v, 0.0f);
            }
            __syncthreads();
            gemv_core(w2_l + (size_t)row0 * DD + cc * 64, DD, 320, am, red,
                      ff2P + (size_t)(rcx * BB) * DD, DD, cc * 64);
            __syncthreads();
        }
        gsync(p.bar, tgt);

        // ---- P11: LN3 (next layer's snw/snb, or final lnow/lnob) ----
        if (bid < BB) {
            const float* nlw = (l < NLAYER - 1) ? p.snw + (l + 1) * DD : p.lnow;
            const float* nlb = (l < NLAYER - 1) ? p.snb + (l + 1) * DD : p.lnob;
            ln_micro(bid, x, b2_l, ff2P, 16, nlw, nlb, xn, sm);
        }
        gsync(p.bar, tgt);
    }

    // ---- P12: final projection, 500 units = rc*125+cc, rows=320 ----
    for (int u = bid; u < 500; u += G) {
        int cc = u % 125, rcx = u / 125, row0 = rcx * 320;
        for (int i = tid; i < 1280; i += 256)
            am[i] = xn[(i / 320) * DD + row0 + (i % 320)];
        __syncthreads();
        gemv_core(p.projw + (size_t)row0 * VV + cc * 64, VV, 320, am, red,
                  projP + (size_t)(rcx * BB) * VV, VV, cc * 64);
        __syncthreads();
    }
    gsync(p.bar, tgt);

    // ---- P13: logits finalize + kv scalar ----
    for (int u = bid; u < 125; u += G) {
        int b = tid >> 6, c = u * 64 + (tid & 63);
        float v = p.projb[c];
#pragma unroll
        for (int j = 0; j < 4; ++j) v += projP[(size_t)(j * BB + b) * VV + c];
        p.out[LG_OFF + (size_t)b * VV + c] = v;
    }
    if (bid == 0 && tid == 0) p.out[KV_IDX] = (float)(HIST + 1);
}

// ---------------- host ----------------
extern "C" void kernel_launch(void* const* d_in, const int* in_sizes, int n_in,
                              void* d_out, int out_size, void* d_ws, size_t ws_size,
                              hipStream_t stream) {
    Prm prm;
    prm.kc    = (const float*)d_in[0];
    prm.vc    = (const float*)d_in[1];
    prm.ck    = (const float*)d_in[2];
    prm.cv    = (const float*)d_in[3];
    prm.ids   = (const int*)d_in[4];
    prm.mflag = (const float*)d_in[7];
    prm.emb   = (const float*)d_in[8];
    prm.pe    = (const float*)d_in[9];
    prm.snw   = (const float*)d_in[10];
    prm.snb   = (const float*)d_in[11];
    prm.wq    = (const float*)d_in[12];
    prm.bq    = (const float*)d_in[13];
    prm.wk    = (const float*)d_in[14];
    prm.wv    = (const float*)d_in[15];
    prm.bv    = (const float*)d_in[16];
    prm.fcw   = (const float*)d_in[17];
    prm.fcb   = (const float*)d_in[18];
    prm.cnw   = (const float*)d_in[19];
    prm.cnb   = (const float*)d_in[20];
    prm.cwq   = (const float*)d_in[21];
    prm.cbq   = (const float*)d_in[22];
    prm.cfcw  = (const float*)d_in[23];
    prm.cfcb  = (const float*)d_in[24];
    prm.mnw   = (const float*)d_in[25];
    prm.mnb   = (const float*)d_in[26];
    prm.w1    = (const float*)d_in[27];
    prm.b1    = (const float*)d_in[28];
    prm.w2    = (const float*)d_in[29];
    prm.b2    = (const float*)d_in[30];
    prm.lnow  = (const float*)d_in[31];
    prm.lnob  = (const float*)d_in[32];
    prm.projw = (const float*)d_in[33];
    prm.projb = (const float*)d_in[34];
    prm.out   = (float*)d_out;
    prm.ws    = (float*)d_ws;
    prm.bar   = (unsigned*)d_ws;     // ws[0]; data buffers start at ws+64 floats

    // Query real co-residency and size the cooperative grid to fit.
    int dev = 0;
    (void)hipGetDevice(&dev);
    int numCU = 0;
    if (hipDeviceGetAttribute(&numCU, hipDeviceAttributeMultiprocessorCount, dev) != hipSuccess || numCU <= 0)
        numCU = 256;
    int maxB = 0;
    if (hipOccupancyMaxActiveBlocksPerMultiprocessor(&maxB, reinterpret_cast<const void*>(mega), 256, 0) != hipSuccess || maxB <= 0)
        maxB = 1;
    int grid = maxB * numCU;
    if (grid > 768) grid = 768;

    bar_init<<<1, 1, 0, stream>>>(prm.bar);
    void* args[] = { &prm };
    hipError_t e = hipLaunchCooperativeKernel(reinterpret_cast<void*>(mega),
                                              dim3(grid), dim3(256), args, 0, stream);
    if (e != hipSuccess) {
        (void)hipGetLastError();   // clear error state
        // Fallback: plain launch. grid <= co-resident capacity, so the
        // persistent-block barrier still completes; spin is bounded anyway.
        hipLaunchKernelGGL(mega, dim3(grid), dim3(256), 0, stream, prm);
    }
}

// Round 9
// 7220.213 us; speedup vs baseline: 1.0152x; 1.0152x over previous
//
#include <hip/hip_runtime.h>

#define BB 4
#define HH 20
#define DHD 64
#define DD 1280
#define DFFN 5120
#define VV 8000
#define HIST 1024
#define TENC 512
#define KVLEN 1025
#define NLAYER 16

static const size_t NK_OFF = 0;
static const size_t NV_OFF = 83968000ull;   // 16*4*20*64*1025
static const size_t LG_OFF = 167936000ull;
static const size_t KV_IDX = 167968000ull;

struct Prm {
    const float *kc, *vc, *ck, *cv;
    const int* ids;
    const float *mflag, *emb, *pe, *snw, *snb, *wq, *bq, *wk, *wv, *bv;
    const float *fcw, *fcb, *cnw, *cnb, *cwq, *cbq, *cfcw, *cfcb, *mnw, *mnb;
    const float *w1, *b1, *w2, *b2, *lnow, *lnob, *projw, *projb;
    float* out;
    float* ws;
    unsigned* bar;
};

__device__ __forceinline__ void fma4(float4& a, float s, const float4& w) {
    a.x += s * w.x; a.y += s * w.y; a.z += s * w.z; a.w += s * w.w;
}

// monotonic grid barrier with exponential-backoff polling.
// device-scope fences handle cross-XCD L2 non-coherence.
__device__ __forceinline__ void gsync(unsigned* bar, unsigned& tgt) {
    __syncthreads();
    if (threadIdx.x == 0) {
        __threadfence();   // release: L2 writeback, device visibility
        unsigned old = __hip_atomic_fetch_add(bar, 1u, __ATOMIC_RELAXED, __HIP_MEMORY_SCOPE_AGENT);
        if (old != tgt - 1u) {   // last arriver skips polling
            int slp = 1, polls = 0;
            while (__hip_atomic_load(bar, __ATOMIC_RELAXED, __HIP_MEMORY_SCOPE_AGENT) < tgt) {
                for (int s = 0; s < slp; ++s) __builtin_amdgcn_s_sleep(8);  // 512 cyc each
                if (slp < 16) slp <<= 1;           // cap ~8192 cyc ≈ 3.4 µs
                if (++polls > (1 << 16)) break;    // bounded: degrade, never hang
            }
        }
        __threadfence();   // acquire: invalidate stale cached lines
    }
    __syncthreads();
    tgt += gridDim.x;
}

__device__ __forceinline__ float blk_red_sum(float v, float* r4) {
#pragma unroll
    for (int o = 32; o; o >>= 1) v += __shfl_xor(v, o, 64);
    int w = threadIdx.x >> 6;
    __syncthreads();
    if ((threadIdx.x & 63) == 0) r4[w] = v;
    __syncthreads();
    return r4[0] + r4[1] + r4[2] + r4[3];
}

// x[b] += rbias + sum_j pin[j][b]; write x; xn[b] = LN(x)*lw+lb.  (block handles batch b)
__device__ void ln_micro(int b, float* x, const float* rbias, const float* pin, int np,
                         const float* lw, const float* lb, float* xn, float* r4) {
    int tid = threadIdx.x;
    float vloc[5]; float s = 0.f;
#pragma unroll
    for (int e = 0; e < 5; ++e) {
        int d = e * 256 + tid;
        float v = x[b * DD + d] + rbias[d];
        for (int j = 0; j < np; ++j) v += pin[(size_t)(j * BB + b) * DD + d];
        vloc[e] = v; s += v;
    }
#pragma unroll
    for (int e = 0; e < 5; ++e) x[b * DD + e * 256 + tid] = vloc[e];
    s = blk_red_sum(s, r4);
    float mean = s * (1.0f / DD);
    float sq = 0.f;
#pragma unroll
    for (int e = 0; e < 5; ++e) { float d0 = vloc[e] - mean; sq += d0 * d0; }
    sq = blk_red_sum(sq, r4);
    float rstd = rsqrtf(sq * (1.0f / DD) + 1e-5f);
#pragma unroll
    for (int e = 0; e < 5; ++e) {
        int d = e * 256 + tid;
        xn[b * DD + d] = (vloc[e] - mean) * rstd * lw[d] + lb[d];
    }
}

// GEMV core: acts am[4][rows] (LDS), W tile rows x 64 cols; writes outp[b*outN + col0 + c].
__device__ __forceinline__ void gemv_core(const float* Wt, int ldw, int rows,
                                          const float* am, float* red,
                                          float* outp, int outN, int col0) {
    int tid = threadIdx.x, cl = tid & 15, sg = tid >> 4;
    float4 a0{0,0,0,0}, a1{0,0,0,0}, a2{0,0,0,0}, a3{0,0,0,0};
    const float* Wp = Wt + cl * 4;
    int iters = rows >> 4;
#pragma unroll 4
    for (int it = 0; it < iters; ++it) {
        int r = sg + it * 16;
        float4 w4 = *(const float4*)(Wp + (size_t)r * ldw);
        fma4(a0, am[r], w4);            fma4(a1, am[rows + r], w4);
        fma4(a2, am[2 * rows + r], w4); fma4(a3, am[3 * rows + r], w4);
    }
    int cq = cl * 4;
    float* rg = red + (size_t)(sg * 4) * 64;
    rg[cq] = a0.x; rg[cq+1] = a0.y; rg[cq+2] = a0.z; rg[cq+3] = a0.w;
    rg += 64; rg[cq] = a1.x; rg[cq+1] = a1.y; rg[cq+2] = a1.z; rg[cq+3] = a1.w;
    rg += 64; rg[cq] = a2.x; rg[cq+1] = a2.y; rg[cq+2] = a2.z; rg[cq+3] = a2.w;
    rg += 64; rg[cq] = a3.x; rg[cq+1] = a3.y; rg[cq+2] = a3.z; rg[cq+3] = a3.w;
    __syncthreads();
    int b = tid >> 6, c = tid & 63;
    float v = 0.f;
#pragma unroll
    for (int g = 0; g < 16; ++g) v += red[(size_t)(g * 4 + b) * 64 + c];
    outp[(size_t)b * outN + col0 + c] = v;
}

__global__ void bar_init(unsigned* bar) { *bar = 0u; }

__global__ __launch_bounds__(256, 3) void mega(Prm p) {
    __shared__ float sm[5376];        // 21.5 KB: red[4096] | am[1280]
    float* red = sm;
    float* am  = sm + 4096;
    // attention aliases (inside red region; phases barrier-separated)
    float* qs    = sm;          // 64
    float* knS   = sm + 64;     // 64
    float* vnS   = sm + 128;    // 64
    float* sc8   = sm + 192;    // [8][128]
    float* parr  = sm + 1216;   // 128
    float* redA  = sm + 1344;   // 128
    float* pvred = sm + 1472;   // [16][64]
    float* snS   = sm + 2496;   // 1

    const int bid = blockIdx.x, tid = threadIdx.x;
    const int G = gridDim.x;
    unsigned tgt = G;

    float* x      = p.ws + 64;
    float* xn     = p.ws + 5184;
    float* qkvp   = p.ws + 10304;    // [24][20][4][64] = 122880
    float* selfS  = p.ws + 133184;   // [4*20*8]*66 = 42240
    float* crossS = p.ws + 175424;   // [4*20*4]*66 = 21120
    float* fcP    = p.ws + 196544;   // [16*4][1280] = 81920
    float* cfcP   = p.ws + 278464;   // 81920
    float* f1P    = p.ws + 360384;   // [8*4][5120] = 163840
    float* ff2P   = p.ws + 524224;   // [16*4][1280] = 81920
    float* projP  = p.ws + 606144;   // [4*4][8000] = 128000

    float* nk = p.out + NK_OFF;
    float* nv = p.out + NV_OFF;
    const float flag = p.mflag[0];

    // ---- P0: embed + LN0 ----
    if (bid < BB) {
        int b = bid, tok = p.ids[b];
        float vloc[5]; float s = 0.f;
#pragma unroll
        for (int e = 0; e < 5; ++e) {
            int d = e * 256 + tid;
            float v = p.emb[(size_t)tok * DD + d] + p.pe[(size_t)HIST * DD + d];
            vloc[e] = v; s += v;
            x[b * DD + d] = v;
        }
        s = blk_red_sum(s, sm);
        float mean = s * (1.0f / DD);
        float sq = 0.f;
#pragma unroll
        for (int e = 0; e < 5; ++e) { float d0 = vloc[e] - mean; sq += d0 * d0; }
        sq = blk_red_sum(sq, sm);
        float rstd = rsqrtf(sq * (1.0f / DD) + 1e-5f);
#pragma unroll
        for (int e = 0; e < 5; ++e) {
            int d = e * 256 + tid;
            xn[b * DD + d] = (vloc[e] - mean) * rstd * p.snw[d] + p.snb[d];
        }
    }
    gsync(p.bar, tgt);

    for (int l = 0; l < NLAYER; ++l) {
        const float* kc_l  = p.kc  + (size_t)l * 5242880;
        const float* vc_l  = p.vc  + (size_t)l * 5242880;
        const float* ck_l  = p.ck  + (size_t)l * 2621440;
        const float* cv_l  = p.cv  + (size_t)l * 2621440;
        float* nk_l = nk + (size_t)l * 5248000;
        float* nv_l = nv + (size_t)l * 5248000;
        const float* wq_l   = p.wq   + (size_t)l * 1638400;
        const float* wk_l   = p.wk   + (size_t)l * 1638400;
        const float* wv_l   = p.wv   + (size_t)l * 1638400;
        const float* cwq_l  = p.cwq  + (size_t)l * 1638400;
        const float* fcw_l  = p.fcw  + (size_t)l * 1638400;
        const float* cfcw_l = p.cfcw + (size_t)l * 1638400;
        const float* bq_l   = p.bq   + (size_t)l * 1280;
        const float* bv_l   = p.bv   + (size_t)l * 1280;
        const float* cbq_l  = p.cbq  + (size_t)l * 1280;
        const float* fcb_l  = p.fcb  + (size_t)l * DD;
        const float* cfcb_l = p.cfcb + (size_t)l * DD;
        const float* w1_l   = p.w1   + (size_t)l * 6553600;
        const float* b1_l   = p.b1   + (size_t)l * DFFN;
        const float* w2_l   = p.w2   + (size_t)l * 6553600;
        const float* b2_l   = p.b2   + (size_t)l * DD;

        // ---- P1: self QKV, 480 units = (mat*20+h)*8 + rc, rows=160 ----
        for (int u = bid; u < 480; u += G) {
            int rc = u & 7, mh = u >> 3, h = mh % 20, mat = mh / 20;
            const float* W = (mat == 0 ? wq_l : mat == 1 ? wk_l : wv_l)
                           + (size_t)h * 81920 + (size_t)rc * 160 * 64;
            for (int i = tid; i < 640; i += 256)
                am[i] = xn[(i / 160) * DD + rc * 160 + (i % 160)];
            __syncthreads();
            gemv_core(W, 64, 160, am, red,
                      qkvp + (size_t)((mat * 8 + rc) * HH + h) * BB * 64, 64, 0);
            __syncthreads();
        }
        gsync(p.bar, tgt);

        // ---- P2: self-attention, 640 units = ((h*4+b)*8)+c, chunk=128 ----
        for (int u = bid; u < 640; u += G) {
            int c = u & 7, hb = u >> 3, b = hb & 3, h = hb >> 2;
            if (tid < 64) {
                float qv = bq_l[h * 64 + tid];
#pragma unroll
                for (int j = 0; j < 8; ++j)
                    qv += qkvp[(size_t)((j * HH + h) * BB + b) * 64 + tid];
                qs[tid] = qv;
            } else if (tid < 128 && c == 0) {
                int t2 = tid - 64;
                float kn = 0.f;
#pragma unroll
                for (int j = 0; j < 8; ++j)
                    kn += qkvp[(size_t)(((8 + j) * HH + h) * BB + b) * 64 + t2];
                knS[t2] = kn;
                nk_l[((size_t)(b * HH + h) * 64 + t2) * KVLEN + HIST] = kn;
            } else if (tid < 192 && c == 0) {
                int t2 = tid - 128;
                float vn = bv_l[h * 64 + t2];
#pragma unroll
                for (int j = 0; j < 8; ++j)
                    vn += qkvp[(size_t)(((16 + j) * HH + h) * BB + b) * 64 + t2];
                vnS[t2] = vn;
                nv_l[(size_t)(b * HH + h) * KVLEN * 64 + (size_t)HIST * 64 + t2] = vn;
            }
            __syncthreads();
            // K phase
            int clK = tid & 31, gK = tid >> 5;
            int jb = c * 128 + clK * 4;
            const float* kb = kc_l + (size_t)(b * HH + h) * 64 * HIST;
            float* nkb = nk_l + (size_t)(b * HH + h) * 64 * KVLEN;
            float ax = 0, ay = 0, az = 0, aw = 0;
#pragma unroll
            for (int it = 0; it < 8; ++it) {
                int dh = gK * 8 + it;
                float4 k4 = *(const float4*)(kb + (size_t)dh * HIST + jb);
                float* nr = nkb + (size_t)dh * KVLEN + jb;
                nr[0] = k4.x; nr[1] = k4.y; nr[2] = k4.z; nr[3] = k4.w;
                float qd = qs[dh];
                ax += qd * k4.x; ay += qd * k4.y; az += qd * k4.z; aw += qd * k4.w;
            }
            sc8[gK * 128 + clK * 4 + 0] = ax; sc8[gK * 128 + clK * 4 + 1] = ay;
            sc8[gK * 128 + clK * 4 + 2] = az; sc8[gK * 128 + clK * 4 + 3] = aw;
            __syncthreads();
            float s = 0.f;
            if (tid < 128) {
#pragma unroll
                for (int g = 0; g < 8; ++g) s += sc8[g * 128 + tid];
                int j = c * 128 + tid;
                if (j != 0) s += -128.0f * flag;
            }
            if (c == 0 && tid < 64) {
                float pp = qs[tid] * knS[tid];
#pragma unroll
                for (int o = 32; o; o >>= 1) pp += __shfl_xor(pp, o, 64);
                if (tid == 0) snS[0] = pp + (-128.0f * flag);
            }
            if (tid < 128) redA[tid] = s;
            __syncthreads();
            for (int st = 64; st; st >>= 1) {
                if (tid < st) redA[tid] = fmaxf(redA[tid], redA[tid + st]);
                __syncthreads();
            }
            float m = redA[0];
            if (c == 0) m = fmaxf(m, snS[0]);
            __syncthreads();
            float pp = 0.f;
            if (tid < 128) { pp = expf(s - m); parr[tid] = pp; redA[tid] = pp; }
            __syncthreads();
            for (int st = 64; st; st >>= 1) {
                if (tid < st) redA[tid] += redA[tid + st];
                __syncthreads();
            }
            float ssum = redA[0];
            float en = (c == 0) ? expf(snS[0] - m) : 0.0f;
            // V phase
            int clV = tid & 15, rg = tid >> 4;
            const float* vb = vc_l + (size_t)(b * HH + h) * HIST * 64;
            float* nvb = nv_l + (size_t)(b * HH + h) * KVLEN * 64;
            float vx = 0, vy = 0, vz = 0, vw = 0;
#pragma unroll
            for (int it = 0; it < 8; ++it) {
                int i = rg * 8 + it;
                size_t jj = (size_t)(c * 128 + i);
                float4 v4 = *(const float4*)(vb + jj * 64 + clV * 4);
                *(float4*)(nvb + jj * 64 + clV * 4) = v4;
                float pw = parr[i];
                vx += pw * v4.x; vy += pw * v4.y; vz += pw * v4.z; vw += pw * v4.w;
            }
            pvred[rg * 64 + clV * 4 + 0] = vx; pvred[rg * 64 + clV * 4 + 1] = vy;
            pvred[rg * 64 + clV * 4 + 2] = vz; pvred[rg * 64 + clV * 4 + 3] = vw;
            __syncthreads();
            float* st_ = selfS + (size_t)((b * HH + h) * 8 + c) * 66;
            if (tid == 0) { st_[0] = m; st_[1] = ssum + en; }
            if (tid < 64) {
                float pv = 0.f;
#pragma unroll
                for (int rgi = 0; rgi < 16; ++rgi) pv += pvred[rgi * 64 + tid];
                if (c == 0) pv += en * vnS[tid];
                st_[2 + tid] = pv;
            }
            __syncthreads();
        }
        gsync(p.bar, tgt);

        // ---- P3: fc out-proj, 320 units = rc*20+cc, rows=80, merge selfS(8) ----
        for (int u = bid; u < 320; u += G) {
            int cc = u % 20, rcx = u / 20, row0 = rcx * 80;
            for (int i = tid; i < 320; i += 256) {
                int b = i / 80, r = i % 80, gr = row0 + r, hh = gr >> 6, dh = gr & 63;
                const float* st = selfS + (size_t)((b * HH + hh) * 8) * 66;
                float M = st[0];
#pragma unroll
                for (int ci = 1; ci < 8; ++ci) M = fmaxf(M, st[ci * 66]);
                float den = 0.f, num = 0.f;
#pragma unroll
                for (int ci = 0; ci < 8; ++ci) {
                    float e = expf(st[ci * 66] - M);
                    den += e * st[ci * 66 + 1];
                    num += e * st[ci * 66 + 2 + dh];
                }
                am[b * 80 + r] = num / den;
            }
            __syncthreads();
            gemv_core(fcw_l + (size_t)row0 * DD + cc * 64, DD, 80, am, red,
                      fcP + (size_t)(rcx * BB) * DD, DD, cc * 64);
            __syncthreads();
        }
        gsync(p.bar, tgt);

        // ---- P4: LN1 ----
        if (bid < BB) ln_micro(bid, x, fcb_l, fcP, 16, p.cnw + l * DD, p.cnb + l * DD, xn, sm);
        gsync(p.bar, tgt);

        // ---- P5: cross Q, 160 units = h*8+rc, rows=160 ----
        for (int u = bid; u < 160; u += G) {
            int rc = u & 7, h = u >> 3;
            const float* W = cwq_l + (size_t)h * 81920 + (size_t)rc * 160 * 64;
            for (int i = tid; i < 640; i += 256)
                am[i] = xn[(i / 160) * DD + rc * 160 + (i % 160)];
            __syncthreads();
            gemv_core(W, 64, 160, am, red,
                      qkvp + (size_t)(rc * HH + h) * BB * 64, 64, 0);
            __syncthreads();
        }
        gsync(p.bar, tgt);

        // ---- P6: cross-attention, 320 units = ((h*4+b)*4)+c, chunk=128 ----
        for (int u = bid; u < 320; u += G) {
            int c = u & 3, hb = u >> 2, b = hb & 3, h = hb >> 2;
            if (tid < 64) {
                float qv = cbq_l[h * 64 + tid];
#pragma unroll
                for (int j = 0; j < 8; ++j)
                    qv += qkvp[(size_t)((j * HH + h) * BB + b) * 64 + tid];
                qs[tid] = qv;
            }
            __syncthreads();
            int clK = tid & 31, gK = tid >> 5;
            int jb = c * 128 + clK * 4;
            const float* kb = ck_l + (size_t)(b * HH + h) * 64 * TENC;
            float ax = 0, ay = 0, az = 0, aw = 0;
#pragma unroll
            for (int it = 0; it < 8; ++it) {
                int dh = gK * 8 + it;
                float4 k4 = *(const float4*)(kb + (size_t)dh * TENC + jb);
                float qd = qs[dh];
                ax += qd * k4.x; ay += qd * k4.y; az += qd * k4.z; aw += qd * k4.w;
            }
            sc8[gK * 128 + clK * 4 + 0] = ax; sc8[gK * 128 + clK * 4 + 1] = ay;
            sc8[gK * 128 + clK * 4 + 2] = az; sc8[gK * 128 + clK * 4 + 3] = aw;
            __syncthreads();
            float s = 0.f;
            if (tid < 128) {
#pragma unroll
                for (int g = 0; g < 8; ++g) s += sc8[g * 128 + tid];
            }
            if (tid < 128) redA[tid] = s;
            __syncthreads();
            for (int st = 64; st; st >>= 1) {
                if (tid < st) redA[tid] = fmaxf(redA[tid], redA[tid + st]);
                __syncthreads();
            }
            float m = redA[0];
            __syncthreads();
            float pp = 0.f;
            if (tid < 128) { pp = expf(s - m); parr[tid] = pp; redA[tid] = pp; }
            __syncthreads();
            for (int st = 64; st; st >>= 1) {
                if (tid < st) redA[tid] += redA[tid + st];
                __syncthreads();
            }
            float ssum = redA[0];
            int clV = tid & 15, rg = tid >> 4;
            const float* vb = cv_l + (size_t)(b * HH + h) * TENC * 64;
            float vx = 0, vy = 0, vz = 0, vw = 0;
#pragma unroll
            for (int it = 0; it < 8; ++it) {
                int i = rg * 8 + it;
                size_t jj = (size_t)(c * 128 + i);
                float4 v4 = *(const float4*)(vb + jj * 64 + clV * 4);
                float pw = parr[i];
                vx += pw * v4.x; vy += pw * v4.y; vz += pw * v4.z; vw += pw * v4.w;
            }
            pvred[rg * 64 + clV * 4 + 0] = vx; pvred[rg * 64 + clV * 4 + 1] = vy;
            pvred[rg * 64 + clV * 4 + 2] = vz; pvred[rg * 64 + clV * 4 + 3] = vw;
            __syncthreads();
            float* st_ = crossS + (size_t)((b * HH + h) * 4 + c) * 66;
            if (tid == 0) { st_[0] = m; st_[1] = ssum; }
            if (tid < 64) {
                float pv = 0.f;
#pragma unroll
                for (int rgi = 0; rgi < 16; ++rgi) pv += pvred[rgi * 64 + tid];
                st_[2 + tid] = pv;
            }
            __syncthreads();
        }
        gsync(p.bar, tgt);

        // ---- P7: cfc out-proj, 320 units, merge crossS(4) ----
        for (int u = bid; u < 320; u += G) {
            int cc = u % 20, rcx = u / 20, row0 = rcx * 80;
            for (int i = tid; i < 320; i += 256) {
                int b = i / 80, r = i % 80, gr = row0 + r, hh = gr >> 6, dh = gr & 63;
                const float* st = crossS + (size_t)((b * HH + hh) * 4) * 66;
                float M = st[0];
#pragma unroll
                for (int ci = 1; ci < 4; ++ci) M = fmaxf(M, st[ci * 66]);
                float den = 0.f, num = 0.f;
#pragma unroll
                for (int ci = 0; ci < 4; ++ci) {
                    float e = expf(st[ci * 66] - M);
                    den += e * st[ci * 66 + 1];
                    num += e * st[ci * 66 + 2 + dh];
                }
                am[b * 80 + r] = num / den;
            }
            __syncthreads();
            gemv_core(cfcw_l + (size_t)row0 * DD + cc * 64, DD, 80, am, red,
                      cfcP + (size_t)(rcx * BB) * DD, DD, cc * 64);
            __syncthreads();
        }
        gsync(p.bar, tgt);

        // ---- P8: LN2 ----
        if (bid < BB) ln_micro(bid, x, cfcb_l, cfcP, 16, p.mnw + l * DD, p.mnb + l * DD, xn, sm);
        gsync(p.bar, tgt);

        // ---- P9: FFN1, 640 units = rc*80+cc, rows=160 ----
        for (int u = bid; u < 640; u += G) {
            int cc = u % 80, rcx = u / 80, row0 = rcx * 160;
            for (int i = tid; i < 640; i += 256)
                am[i] = xn[(i / 160) * DD + row0 + (i % 160)];
            __syncthreads();
            gemv_core(w1_l + (size_t)row0 * DFFN + cc * 64, DFFN, 160, am, red,
                      f1P + (size_t)(rcx * BB) * DFFN, DFFN, cc * 64);
            __syncthreads();
        }
        gsync(p.bar, tgt);

        // ---- P10: FFN2, 320 units = rc*20+cc, rows=320, relu-merge f1P(8) ----
        for (int u = bid; u < 320; u += G) {
            int cc = u % 20, rcx = u / 20, row0 = rcx * 320;
            for (int i = tid; i < 1280; i += 256) {
                int b = i / 320, r = i % 320;
                float v = b1_l[row0 + r];
#pragma unroll
                for (int j = 0; j < 8; ++j)
                    v += f1P[(size_t)(j * BB + b) * DFFN + row0 + r];
                am[i] = fmaxf(v, 0.0f);
            }
            __syncthreads();
            gemv_core(w2_l + (size_t)row0 * DD + cc * 64, DD, 320, am, red,
                      ff2P + (size_t)(rcx * BB) * DD, DD, cc * 64);
            __syncthreads();
        }
        gsync(p.bar, tgt);

        // ---- P11: LN3 (next layer's snw/snb, or final lnow/lnob) ----
        if (bid < BB) {
            const float* nlw = (l < NLAYER - 1) ? p.snw + (l + 1) * DD : p.lnow;
            const float* nlb = (l < NLAYER - 1) ? p.snb + (l + 1) * DD : p.lnob;
            ln_micro(bid, x, b2_l, ff2P, 16, nlw, nlb, xn, sm);
        }
        gsync(p.bar, tgt);
    }

    // ---- P12: final projection, 500 units = rc*125+cc, rows=320 ----
    for (int u = bid; u < 500; u += G) {
        int cc = u % 125, rcx = u / 125, row0 = rcx * 320;
        for (int i = tid; i < 1280; i += 256)
            am[i] = xn[(i / 320) * DD + row0 + (i % 320)];
        __syncthreads();
        gemv_core(p.projw + (size_t)row0 * VV + cc * 64, VV, 320, am, red,
                  projP + (size_t)(rcx * BB) * VV, VV, cc * 64);
        __syncthreads();
    }
    gsync(p.bar, tgt);

    // ---- P13: logits finalize + kv scalar ----
    for (int u = bid; u < 125; u += G) {
        int b = tid >> 6, c = u * 64 + (tid & 63);
        float v = p.projb[c];
#pragma unroll
        for (int j = 0; j < 4; ++j) v += projP[(size_t)(j * BB + b) * VV + c];
        p.out[LG_OFF + (size_t)b * VV + c] = v;
    }
    if (bid == 0 && tid == 0) p.out[KV_IDX] = (float)(HIST + 1);
}

// ---------------- host ----------------
extern "C" void kernel_launch(void* const* d_in, const int* in_sizes, int n_in,
                              void* d_out, int out_size, void* d_ws, size_t ws_size,
                              hipStream_t stream) {
    Prm prm;
    prm.kc    = (const float*)d_in[0];
    prm.vc    = (const float*)d_in[1];
    prm.ck    = (const float*)d_in[2];
    prm.cv    = (const float*)d_in[3];
    prm.ids   = (const int*)d_in[4];
    prm.mflag = (const float*)d_in[7];
    prm.emb   = (const float*)d_in[8];
    prm.pe    = (const float*)d_in[9];
    prm.snw   = (const float*)d_in[10];
    prm.snb   = (const float*)d_in[11];
    prm.wq    = (const float*)d_in[12];
    prm.bq    = (const float*)d_in[13];
    prm.wk    = (const float*)d_in[14];
    prm.wv    = (const float*)d_in[15];
    prm.bv    = (const float*)d_in[16];
    prm.fcw   = (const float*)d_in[17];
    prm.fcb   = (const float*)d_in[18];
    prm.cnw   = (const float*)d_in[19];
    prm.cnb   = (const float*)d_in[20];
    prm.cwq   = (const float*)d_in[21];
    prm.cbq   = (const float*)d_in[22];
    prm.cfcw  = (const float*)d_in[23];
    prm.cfcb  = (const float*)d_in[24];
    prm.mnw   = (const float*)d_in[25];
    prm.mnb   = (const float*)d_in[26];
    prm.w1    = (const float*)d_in[27];
    prm.b1    = (const float*)d_in[28];
    prm.w2    = (const float*)d_in[29];
    prm.b2    = (const float*)d_in[30];
    prm.lnow  = (const float*)d_in[31];
    prm.lnob  = (const float*)d_in[32];
    prm.projw = (const float*)d_in[33];
    prm.projb = (const float*)d_in[34];
    prm.out   = (float*)d_out;
    prm.ws    = (float*)d_ws;
    prm.bar   = (unsigned*)d_ws;     // ws[0]; data buffers start at ws+64 floats

    // Query real co-residency and size the cooperative grid to fit.
    int dev = 0;
    (void)hipGetDevice(&dev);
    int numCU = 0;
    if (hipDeviceGetAttribute(&numCU, hipDeviceAttributeMultiprocessorCount, dev) != hipSuccess || numCU <= 0)
        numCU = 256;
    int maxB = 0;
    if (hipOccupancyMaxActiveBlocksPerMultiprocessor(&maxB, reinterpret_cast<const void*>(mega), 256, 0) != hipSuccess || maxB <= 0)
        maxB = 1;
    int grid = maxB * numCU;
    if (grid > 768) grid = 768;

    bar_init<<<1, 1, 0, stream>>>(prm.bar);
    void* args[] = { &prm };
    hipError_t e = hipLaunchCooperativeKernel(reinterpret_cast<void*>(mega),
                                              dim3(grid), dim3(256), args, 0, stream);
    if (e != hipSuccess) {
        (void)hipGetLastError();   // clear error state
        // Fallback: plain launch. grid <= co-resident capacity, so the
        // persistent-block barrier still completes; spin is bounded anyway.
        hipLaunchKernelGGL(mega, dim3(grid), dim3(256), 0, stream, prm);
    }
}

// Round 10
// 5247.820 us; speedup vs baseline: 1.3967x; 1.3759x over previous
//
#include <hip/hip_runtime.h>

#define BB 4
#define HH 20
#define DHD 64
#define DD 1280
#define DFFN 5120
#define VV 8000
#define HIST 1024
#define TENC 512
#define KVLEN 1025
#define NLAYER 16

static const size_t NK_OFF = 0;
static const size_t NV_OFF = 83968000ull;   // 16*4*20*64*1025
static const size_t LG_OFF = 167936000ull;
static const size_t KV_IDX = 167968000ull;

struct Prm {
    const float *kc, *vc, *ck, *cv;
    const int* ids;
    const float *mflag, *emb, *pe, *snw, *snb, *wq, *bq, *wk, *wv, *bv;
    const float *fcw, *fcb, *cnw, *cnb, *cwq, *cbq, *cfcw, *cfcb, *mnw, *mnb;
    const float *w1, *b1, *w2, *b2, *lnow, *lnob, *projw, *projb;
    float* out;
    float* ws;
    unsigned* bar;
};

__device__ __forceinline__ void fma4(float4& a, float s, const float4& w) {
    a.x += s * w.x; a.y += s * w.y; a.z += s * w.z; a.w += s * w.w;
}

// Device-coherent (agent-scope, sc1) scalar access for cross-block intermediates.
// These bypass the non-coherent per-XCD L2, so grid barriers need NO L2 wb/inv.
__device__ __forceinline__ float ld_coh(const float* p) {
    return __hip_atomic_load(p, __ATOMIC_RELAXED, __HIP_MEMORY_SCOPE_AGENT);
}
__device__ __forceinline__ void st_coh(float* p, float v) {
    __hip_atomic_store(p, v, __ATOMIC_RELAXED, __HIP_MEMORY_SCOPE_AGENT);
}

// monotonic grid barrier, fence-free: all cross-block data uses sc1 accesses,
// which are visible at the device coherent point once retired. __syncthreads()
// drains vmcnt for all waves (HIP semantics) before we signal arrival.
__device__ __forceinline__ void gsync(unsigned* bar, unsigned& tgt) {
    __syncthreads();
    if (threadIdx.x == 0) {
        asm volatile("s_waitcnt vmcnt(0) lgkmcnt(0)" ::: "memory");  // defensive drain
        unsigned old = __hip_atomic_fetch_add(bar, 1u, __ATOMIC_RELAXED, __HIP_MEMORY_SCOPE_AGENT);
        if (old != tgt - 1u) {   // last arriver skips polling
            int slp = 1, polls = 0;
            while (__hip_atomic_load(bar, __ATOMIC_RELAXED, __HIP_MEMORY_SCOPE_AGENT) < tgt) {
                for (int s = 0; s < slp; ++s) __builtin_amdgcn_s_sleep(8);  // 512 cyc each
                if (slp < 4) slp <<= 1;            // cap ~2048 cyc ≈ 0.9 µs
                if (++polls > (1 << 17)) break;    // bounded: degrade, never hang
            }
        }
    }
    __syncthreads();
    tgt += gridDim.x;
}

__device__ __forceinline__ float blk_red_sum(float v, float* r4) {
#pragma unroll
    for (int o = 32; o; o >>= 1) v += __shfl_xor(v, o, 64);
    int w = threadIdx.x >> 6;
    __syncthreads();
    if ((threadIdx.x & 63) == 0) r4[w] = v;
    __syncthreads();
    return r4[0] + r4[1] + r4[2] + r4[3];
}

// x[b] += rbias + sum_j pin[j][b]; write x; xn[b] = LN(x)*lw+lb.  (block handles batch b)
__device__ void ln_micro(int b, float* x, const float* rbias, const float* pin, int np,
                         const float* lw, const float* lb, float* xn, float* r4) {
    int tid = threadIdx.x;
    float vloc[5]; float s = 0.f;
#pragma unroll
    for (int e = 0; e < 5; ++e) {
        int d = e * 256 + tid;
        float v = ld_coh(&x[b * DD + d]) + rbias[d];
        for (int j = 0; j < np; ++j) v += ld_coh(&pin[(size_t)(j * BB + b) * DD + d]);
        vloc[e] = v; s += v;
    }
#pragma unroll
    for (int e = 0; e < 5; ++e) st_coh(&x[b * DD + e * 256 + tid], vloc[e]);
    s = blk_red_sum(s, r4);
    float mean = s * (1.0f / DD);
    float sq = 0.f;
#pragma unroll
    for (int e = 0; e < 5; ++e) { float d0 = vloc[e] - mean; sq += d0 * d0; }
    sq = blk_red_sum(sq, r4);
    float rstd = rsqrtf(sq * (1.0f / DD) + 1e-5f);
#pragma unroll
    for (int e = 0; e < 5; ++e) {
        int d = e * 256 + tid;
        st_coh(&xn[b * DD + d], (vloc[e] - mean) * rstd * lw[d] + lb[d]);
    }
}

// GEMV core: acts am[4][rows] (LDS), W tile rows x 64 cols; coherent-writes outp.
__device__ __forceinline__ void gemv_core(const float* Wt, int ldw, int rows,
                                          const float* am, float* red,
                                          float* outp, int outN, int col0) {
    int tid = threadIdx.x, cl = tid & 15, sg = tid >> 4;
    float4 a0{0,0,0,0}, a1{0,0,0,0}, a2{0,0,0,0}, a3{0,0,0,0};
    const float* Wp = Wt + cl * 4;
    int iters = rows >> 4;
#pragma unroll 4
    for (int it = 0; it < iters; ++it) {
        int r = sg + it * 16;
        float4 w4 = *(const float4*)(Wp + (size_t)r * ldw);
        fma4(a0, am[r], w4);            fma4(a1, am[rows + r], w4);
        fma4(a2, am[2 * rows + r], w4); fma4(a3, am[3 * rows + r], w4);
    }
    int cq = cl * 4;
    float* rg = red + (size_t)(sg * 4) * 64;
    rg[cq] = a0.x; rg[cq+1] = a0.y; rg[cq+2] = a0.z; rg[cq+3] = a0.w;
    rg += 64; rg[cq] = a1.x; rg[cq+1] = a1.y; rg[cq+2] = a1.z; rg[cq+3] = a1.w;
    rg += 64; rg[cq] = a2.x; rg[cq+1] = a2.y; rg[cq+2] = a2.z; rg[cq+3] = a2.w;
    rg += 64; rg[cq] = a3.x; rg[cq+1] = a3.y; rg[cq+2] = a3.z; rg[cq+3] = a3.w;
    __syncthreads();
    int b = tid >> 6, c = tid & 63;
    float v = 0.f;
#pragma unroll
    for (int g = 0; g < 16; ++g) v += red[(size_t)(g * 4 + b) * 64 + c];
    st_coh(&outp[(size_t)b * outN + col0 + c], v);
}

__global__ void bar_init(unsigned* bar) { *bar = 0u; }

__global__ __launch_bounds__(256, 3) void mega(Prm p) {
    __shared__ float sm[5376];        // 21.5 KB: red[4096] | am[1280]
    float* red = sm;
    float* am  = sm + 4096;
    // attention aliases (inside red region; phases barrier-separated)
    float* qs    = sm;          // 64
    float* knS   = sm + 64;     // 64
    float* vnS   = sm + 128;    // 64
    float* sc8   = sm + 192;    // [8][128]
    float* parr  = sm + 1216;   // 128
    float* redA  = sm + 1344;   // 128
    float* pvred = sm + 1472;   // [16][64]
    float* snS   = sm + 2496;   // 1

    const int bid = blockIdx.x, tid = threadIdx.x;
    const int G = gridDim.x;
    unsigned tgt = G;

    float* x      = p.ws + 64;
    float* xn     = p.ws + 5184;
    float* qkvp   = p.ws + 10304;    // [24][20][4][64] = 122880
    float* selfS  = p.ws + 133184;   // [4*20*8]*66 = 42240
    float* crossS = p.ws + 175424;   // [4*20*4]*66 = 21120
    float* fcP    = p.ws + 196544;   // [16*4][1280] = 81920
    float* cfcP   = p.ws + 278464;   // 81920
    float* f1P    = p.ws + 360384;   // [8*4][5120] = 163840
    float* ff2P   = p.ws + 524224;   // [16*4][1280] = 81920
    float* projP  = p.ws + 606144;   // [4*4][8000] = 128000

    float* nk = p.out + NK_OFF;
    float* nv = p.out + NV_OFF;
    const float flag = p.mflag[0];

    // ---- P0: embed + LN0 ----
    if (bid < BB) {
        int b = bid, tok = p.ids[b];
        float vloc[5]; float s = 0.f;
#pragma unroll
        for (int e = 0; e < 5; ++e) {
            int d = e * 256 + tid;
            float v = p.emb[(size_t)tok * DD + d] + p.pe[(size_t)HIST * DD + d];
            vloc[e] = v; s += v;
            st_coh(&x[b * DD + d], v);
        }
        s = blk_red_sum(s, sm);
        float mean = s * (1.0f / DD);
        float sq = 0.f;
#pragma unroll
        for (int e = 0; e < 5; ++e) { float d0 = vloc[e] - mean; sq += d0 * d0; }
        sq = blk_red_sum(sq, sm);
        float rstd = rsqrtf(sq * (1.0f / DD) + 1e-5f);
#pragma unroll
        for (int e = 0; e < 5; ++e) {
            int d = e * 256 + tid;
            st_coh(&xn[b * DD + d], (vloc[e] - mean) * rstd * p.snw[d] + p.snb[d]);
        }
    }
    gsync(p.bar, tgt);

    for (int l = 0; l < NLAYER; ++l) {
        const float* kc_l  = p.kc  + (size_t)l * 5242880;
        const float* vc_l  = p.vc  + (size_t)l * 5242880;
        const float* ck_l  = p.ck  + (size_t)l * 2621440;
        const float* cv_l  = p.cv  + (size_t)l * 2621440;
        float* nk_l = nk + (size_t)l * 5248000;
        float* nv_l = nv + (size_t)l * 5248000;
        const float* wq_l   = p.wq   + (size_t)l * 1638400;
        const float* wk_l   = p.wk   + (size_t)l * 1638400;
        const float* wv_l   = p.wv   + (size_t)l * 1638400;
        const float* cwq_l  = p.cwq  + (size_t)l * 1638400;
        const float* fcw_l  = p.fcw  + (size_t)l * 1638400;
        const float* cfcw_l = p.cfcw + (size_t)l * 1638400;
        const float* bq_l   = p.bq   + (size_t)l * 1280;
        const float* bv_l   = p.bv   + (size_t)l * 1280;
        const float* cbq_l  = p.cbq  + (size_t)l * 1280;
        const float* fcb_l  = p.fcb  + (size_t)l * DD;
        const float* cfcb_l = p.cfcb + (size_t)l * DD;
        const float* w1_l   = p.w1   + (size_t)l * 6553600;
        const float* b1_l   = p.b1   + (size_t)l * DFFN;
        const float* w2_l   = p.w2   + (size_t)l * 6553600;
        const float* b2_l   = p.b2   + (size_t)l * DD;

        // ---- P1: self QKV, 480 units = (mat*20+h)*8 + rc, rows=160 ----
        for (int u = bid; u < 480; u += G) {
            int rc = u & 7, mh = u >> 3, h = mh % 20, mat = mh / 20;
            const float* W = (mat == 0 ? wq_l : mat == 1 ? wk_l : wv_l)
                           + (size_t)h * 81920 + (size_t)rc * 160 * 64;
            for (int i = tid; i < 640; i += 256)
                am[i] = ld_coh(&xn[(i / 160) * DD + rc * 160 + (i % 160)]);
            __syncthreads();
            gemv_core(W, 64, 160, am, red,
                      qkvp + (size_t)((mat * 8 + rc) * HH + h) * BB * 64, 64, 0);
            __syncthreads();
        }
        gsync(p.bar, tgt);

        // ---- P2: self-attention, 640 units = ((h*4+b)*8)+c, chunk=128 ----
        for (int u = bid; u < 640; u += G) {
            int c = u & 7, hb = u >> 3, b = hb & 3, h = hb >> 2;
            if (tid < 64) {
                float qv = bq_l[h * 64 + tid];
#pragma unroll
                for (int j = 0; j < 8; ++j)
                    qv += ld_coh(&qkvp[(size_t)((j * HH + h) * BB + b) * 64 + tid]);
                qs[tid] = qv;
            } else if (tid < 128 && c == 0) {
                int t2 = tid - 64;
                float kn = 0.f;
#pragma unroll
                for (int j = 0; j < 8; ++j)
                    kn += ld_coh(&qkvp[(size_t)(((8 + j) * HH + h) * BB + b) * 64 + t2]);
                knS[t2] = kn;
                nk_l[((size_t)(b * HH + h) * 64 + t2) * KVLEN + HIST] = kn;
            } else if (tid < 192 && c == 0) {
                int t2 = tid - 128;
                float vn = bv_l[h * 64 + t2];
#pragma unroll
                for (int j = 0; j < 8; ++j)
                    vn += ld_coh(&qkvp[(size_t)(((16 + j) * HH + h) * BB + b) * 64 + t2]);
                vnS[t2] = vn;
                nv_l[(size_t)(b * HH + h) * KVLEN * 64 + (size_t)HIST * 64 + t2] = vn;
            }
            __syncthreads();
            // K phase
            int clK = tid & 31, gK = tid >> 5;
            int jb = c * 128 + clK * 4;
            const float* kb = kc_l + (size_t)(b * HH + h) * 64 * HIST;
            float* nkb = nk_l + (size_t)(b * HH + h) * 64 * KVLEN;
            float ax = 0, ay = 0, az = 0, aw = 0;
#pragma unroll
            for (int it = 0; it < 8; ++it) {
                int dh = gK * 8 + it;
                float4 k4 = *(const float4*)(kb + (size_t)dh * HIST + jb);
                float* nr = nkb + (size_t)dh * KVLEN + jb;
                nr[0] = k4.x; nr[1] = k4.y; nr[2] = k4.z; nr[3] = k4.w;
                float qd = qs[dh];
                ax += qd * k4.x; ay += qd * k4.y; az += qd * k4.z; aw += qd * k4.w;
            }
            sc8[gK * 128 + clK * 4 + 0] = ax; sc8[gK * 128 + clK * 4 + 1] = ay;
            sc8[gK * 128 + clK * 4 + 2] = az; sc8[gK * 128 + clK * 4 + 3] = aw;
            __syncthreads();
            float s = 0.f;
            if (tid < 128) {
#pragma unroll
                for (int g = 0; g < 8; ++g) s += sc8[g * 128 + tid];
                int j = c * 128 + tid;
                if (j != 0) s += -128.0f * flag;
            }
            if (c == 0 && tid < 64) {
                float pp = qs[tid] * knS[tid];
#pragma unroll
                for (int o = 32; o; o >>= 1) pp += __shfl_xor(pp, o, 64);
                if (tid == 0) snS[0] = pp + (-128.0f * flag);
            }
            if (tid < 128) redA[tid] = s;
            __syncthreads();
            for (int st = 64; st; st >>= 1) {
                if (tid < st) redA[tid] = fmaxf(redA[tid], redA[tid + st]);
                __syncthreads();
            }
            float m = redA[0];
            if (c == 0) m = fmaxf(m, snS[0]);
            __syncthreads();
            float pp = 0.f;
            if (tid < 128) { pp = expf(s - m); parr[tid] = pp; redA[tid] = pp; }
            __syncthreads();
            for (int st = 64; st; st >>= 1) {
                if (tid < st) redA[tid] += redA[tid + st];
                __syncthreads();
            }
            float ssum = redA[0];
            float en = (c == 0) ? expf(snS[0] - m) : 0.0f;
            // V phase
            int clV = tid & 15, rg = tid >> 4;
            const float* vb = vc_l + (size_t)(b * HH + h) * HIST * 64;
            float* nvb = nv_l + (size_t)(b * HH + h) * KVLEN * 64;
            float vx = 0, vy = 0, vz = 0, vw = 0;
#pragma unroll
            for (int it = 0; it < 8; ++it) {
                int i = rg * 8 + it;
                size_t jj = (size_t)(c * 128 + i);
                float4 v4 = *(const float4*)(vb + jj * 64 + clV * 4);
                *(float4*)(nvb + jj * 64 + clV * 4) = v4;
                float pw = parr[i];
                vx += pw * v4.x; vy += pw * v4.y; vz += pw * v4.z; vw += pw * v4.w;
            }
            pvred[rg * 64 + clV * 4 + 0] = vx; pvred[rg * 64 + clV * 4 + 1] = vy;
            pvred[rg * 64 + clV * 4 + 2] = vz; pvred[rg * 64 + clV * 4 + 3] = vw;
            __syncthreads();
            float* st_ = selfS + (size_t)((b * HH + h) * 8 + c) * 66;
            if (tid == 0) { st_co_init:
                st_coh(&st_[0], m); st_coh(&st_[1], ssum + en);
            }
            if (tid < 64) {
                float pv = 0.f;
#pragma unroll
                for (int rgi = 0; rgi < 16; ++rgi) pv += pvred[rgi * 64 + tid];
                if (c == 0) pv += en * vnS[tid];
                st_coh(&st_[2 + tid], pv);
            }
            __syncthreads();
        }
        gsync(p.bar, tgt);

        // ---- P3: fc out-proj, 320 units = rc*20+cc, rows=80, merge selfS(8) ----
        for (int u = bid; u < 320; u += G) {
            int cc = u % 20, rcx = u / 20, row0 = rcx * 80;
            for (int i = tid; i < 320; i += 256) {
                int b = i / 80, r = i % 80, gr = row0 + r, hh = gr >> 6, dh = gr & 63;
                const float* st = selfS + (size_t)((b * HH + hh) * 8) * 66;
                float M = ld_coh(&st[0]);
#pragma unroll
                for (int ci = 1; ci < 8; ++ci) M = fmaxf(M, ld_coh(&st[ci * 66]));
                float den = 0.f, num = 0.f;
#pragma unroll
                for (int ci = 0; ci < 8; ++ci) {
                    float e = expf(ld_coh(&st[ci * 66]) - M);
                    den += e * ld_coh(&st[ci * 66 + 1]);
                    num += e * ld_coh(&st[ci * 66 + 2 + dh]);
                }
                am[b * 80 + r] = num / den;
            }
            __syncthreads();
            gemv_core(fcw_l + (size_t)row0 * DD + cc * 64, DD, 80, am, red,
                      fcP + (size_t)(rcx * BB) * DD, DD, cc * 64);
            __syncthreads();
        }
        gsync(p.bar, tgt);

        // ---- P4: LN1 ----
        if (bid < BB) ln_micro(bid, x, fcb_l, fcP, 16, p.cnw + l * DD, p.cnb + l * DD, xn, sm);
        gsync(p.bar, tgt);

        // ---- P5: cross Q, 160 units = h*8+rc, rows=160 ----
        for (int u = bid; u < 160; u += G) {
            int rc = u & 7, h = u >> 3;
            const float* W = cwq_l + (size_t)h * 81920 + (size_t)rc * 160 * 64;
            for (int i = tid; i < 640; i += 256)
                am[i] = ld_coh(&xn[(i / 160) * DD + rc * 160 + (i % 160)]);
            __syncthreads();
            gemv_core(W, 64, 160, am, red,
                      qkvp + (size_t)(rc * HH + h) * BB * 64, 64, 0);
            __syncthreads();
        }
        gsync(p.bar, tgt);

        // ---- P6: cross-attention, 320 units = ((h*4+b)*4)+c, chunk=128 ----
        for (int u = bid; u < 320; u += G) {
            int c = u & 3, hb = u >> 2, b = hb & 3, h = hb >> 2;
            if (tid < 64) {
                float qv = cbq_l[h * 64 + tid];
#pragma unroll
                for (int j = 0; j < 8; ++j)
                    qv += ld_coh(&qkvp[(size_t)((j * HH + h) * BB + b) * 64 + tid]);
                qs[tid] = qv;
            }
            __syncthreads();
            int clK = tid & 31, gK = tid >> 5;
            int jb = c * 128 + clK * 4;
            const float* kb = ck_l + (size_t)(b * HH + h) * 64 * TENC;
            float ax = 0, ay = 0, az = 0, aw = 0;
#pragma unroll
            for (int it = 0; it < 8; ++it) {
                int dh = gK * 8 + it;
                float4 k4 = *(const float4*)(kb + (size_t)dh * TENC + jb);
                float qd = qs[dh];
                ax += qd * k4.x; ay += qd * k4.y; az += qd * k4.z; aw += qd * k4.w;
            }
            sc8[gK * 128 + clK * 4 + 0] = ax; sc8[gK * 128 + clK * 4 + 1] = ay;
            sc8[gK * 128 + clK * 4 + 2] = az; sc8[gK * 128 + clK * 4 + 3] = aw;
            __syncthreads();
            float s = 0.f;
            if (tid < 128) {
#pragma unroll
                for (int g = 0; g < 8; ++g) s += sc8[g * 128 + tid];
            }
            if (tid < 128) redA[tid] = s;
            __syncthreads();
            for (int st = 64; st; st >>= 1) {
                if (tid < st) redA[tid] = fmaxf(redA[tid], redA[tid + st]);
                __syncthreads();
            }
            float m = redA[0];
            __syncthreads();
            float pp = 0.f;
            if (tid < 128) { pp = expf(s - m); parr[tid] = pp; redA[tid] = pp; }
            __syncthreads();
            for (int st = 64; st; st >>= 1) {
                if (tid < st) redA[tid] += redA[tid + st];
                __syncthreads();
            }
            float ssum = redA[0];
            int clV = tid & 15, rg = tid >> 4;
            const float* vb = cv_l + (size_t)(b * HH + h) * TENC * 64;
            float vx = 0, vy = 0, vz = 0, vw = 0;
#pragma unroll
            for (int it = 0; it < 8; ++it) {
                int i = rg * 8 + it;
                size_t jj = (size_t)(c * 128 + i);
                float4 v4 = *(const float4*)(vb + jj * 64 + clV * 4);
                float pw = parr[i];
                vx += pw * v4.x; vy += pw * v4.y; vz += pw * v4.z; vw += pw * v4.w;
            }
            pvred[rg * 64 + clV * 4 + 0] = vx; pvred[rg * 64 + clV * 4 + 1] = vy;
            pvred[rg * 64 + clV * 4 + 2] = vz; pvred[rg * 64 + clV * 4 + 3] = vw;
            __syncthreads();
            float* st_ = crossS + (size_t)((b * HH + h) * 4 + c) * 66;
            if (tid == 0) { st_coh(&st_[0], m); st_coh(&st_[1], ssum); }
            if (tid < 64) {
                float pv = 0.f;
#pragma unroll
                for (int rgi = 0; rgi < 16; ++rgi) pv += pvred[rgi * 64 + tid];
                st_coh(&st_[2 + tid], pv);
            }
            __syncthreads();
        }
        gsync(p.bar, tgt);

        // ---- P7: cfc out-proj, 320 units, merge crossS(4) ----
        for (int u = bid; u < 320; u += G) {
            int cc = u % 20, rcx = u / 20, row0 = rcx * 80;
            for (int i = tid; i < 320; i += 256) {
                int b = i / 80, r = i % 80, gr = row0 + r, hh = gr >> 6, dh = gr & 63;
                const float* st = crossS + (size_t)((b * HH + hh) * 4) * 66;
                float M = ld_coh(&st[0]);
#pragma unroll
                for (int ci = 1; ci < 4; ++ci) M = fmaxf(M, ld_coh(&st[ci * 66]));
                float den = 0.f, num = 0.f;
#pragma unroll
                for (int ci = 0; ci < 4; ++ci) {
                    float e = expf(ld_coh(&st[ci * 66]) - M);
                    den += e * ld_coh(&st[ci * 66 + 1]);
                    num += e * ld_coh(&st[ci * 66 + 2 + dh]);
                }
                am[b * 80 + r] = num / den;
            }
            __syncthreads();
            gemv_core(cfcw_l + (size_t)row0 * DD + cc * 64, DD, 80, am, red,
                      cfcP + (size_t)(rcx * BB) * DD, DD, cc * 64);
            __syncthreads();
        }
        gsync(p.bar, tgt);

        // ---- P8: LN2 ----
        if (bid < BB) ln_micro(bid, x, cfcb_l, cfcP, 16, p.mnw + l * DD, p.mnb + l * DD, xn, sm);
        gsync(p.bar, tgt);

        // ---- P9: FFN1, 640 units = rc*80+cc, rows=160 ----
        for (int u = bid; u < 640; u += G) {
            int cc = u % 80, rcx = u / 80, row0 = rcx * 160;
            for (int i = tid; i < 640; i += 256)
                am[i] = ld_coh(&xn[(i / 160) * DD + row0 + (i % 160)]);
            __syncthreads();
            gemv_core(w1_l + (size_t)row0 * DFFN + cc * 64, DFFN, 160, am, red,
                      f1P + (size_t)(rcx * BB) * DFFN, DFFN, cc * 64);
            __syncthreads();
        }
        gsync(p.bar, tgt);

        // ---- P10: FFN2, 320 units = rc*20+cc, rows=320, relu-merge f1P(8) ----
        for (int u = bid; u < 320; u += G) {
            int cc = u % 20, rcx = u / 20, row0 = rcx * 320;
            for (int i = tid; i < 1280; i += 256) {
                int b = i / 320, r = i % 320;
                float v = b1_l[row0 + r];
#pragma unroll
                for (int j = 0; j < 8; ++j)
                    v += ld_coh(&f1P[(size_t)(j * BB + b) * DFFN + row0 + r]);
                am[i] = fmaxf(v, 0.0f);
            }
            __syncthreads();
            gemv_core(w2_l + (size_t)row0 * DD + cc * 64, DD, 320, am, red,
                      ff2P + (size_t)(rcx * BB) * DD, DD, cc * 64);
            __syncthreads();
        }
        gsync(p.bar, tgt);

        // ---- P11: LN3 (next layer's snw/snb, or final lnow/lnob) ----
        if (bid < BB) {
            const float* nlw = (l < NLAYER - 1) ? p.snw + (l + 1) * DD : p.lnow;
            const float* nlb = (l < NLAYER - 1) ? p.snb + (l + 1) * DD : p.lnob;
            ln_micro(bid, x, b2_l, ff2P, 16, nlw, nlb, xn, sm);
        }
        gsync(p.bar, tgt);
    }

    // ---- P12: final projection, 500 units = rc*125+cc, rows=320 ----
    for (int u = bid; u < 500; u += G) {
        int cc = u % 125, rcx = u / 125, row0 = rcx * 320;
        for (int i = tid; i < 1280; i += 256)
            am[i] = ld_coh(&xn[(i / 320) * DD + row0 + (i % 320)]);
        __syncthreads();
        gemv_core(p.projw + (size_t)row0 * VV + cc * 64, VV, 320, am, red,
                  projP + (size_t)(rcx * BB) * VV, VV, cc * 64);
        __syncthreads();
    }
    gsync(p.bar, tgt);

    // ---- P13: logits finalize + kv scalar ----
    for (int u = bid; u < 125; u += G) {
        int b = tid >> 6, c = u * 64 + (tid & 63);
        float v = p.projb[c];
#pragma unroll
        for (int j = 0; j < 4; ++j) v += ld_coh(&projP[(size_t)(j * BB + b) * VV + c]);
        p.out[LG_OFF + (size_t)b * VV + c] = v;
    }
    if (bid == 0 && tid == 0) p.out[KV_IDX] = (float)(HIST + 1);
}

// ---------------- host ----------------
extern "C" void kernel_launch(void* const* d_in, const int* in_sizes, int n_in,
                              void* d_out, int out_size, void* d_ws, size_t ws_size,
                              hipStream_t stream) {
    Prm prm;
    prm.kc    = (const float*)d_in[0];
    prm.vc    = (const float*)d_in[1];
    prm.ck    = (const float*)d_in[2];
    prm.cv    = (const float*)d_in[3];
    prm.ids   = (const int*)d_in[4];
    prm.mflag = (const float*)d_in[7];
    prm.emb   = (const float*)d_in[8];
    prm.pe    = (const float*)d_in[9];
    prm.snw   = (const float*)d_in[10];
    prm.snb   = (const float*)d_in[11];
    prm.wq    = (const float*)d_in[12];
    prm.bq    = (const float*)d_in[13];
    prm.wk    = (const float*)d_in[14];
    prm.wv    = (const float*)d_in[15];
    prm.bv    = (const float*)d_in[16];
    prm.fcw   = (const float*)d_in[17];
    prm.fcb   = (const float*)d_in[18];
    prm.cnw   = (const float*)d_in[19];
    prm.cnb   = (const float*)d_in[20];
    prm.cwq   = (const float*)d_in[21];
    prm.cbq   = (const float*)d_in[22];
    prm.cfcw  = (const float*)d_in[23];
    prm.cfcb  = (const float*)d_in[24];
    prm.mnw   = (const float*)d_in[25];
    prm.mnb   = (const float*)d_in[26];
    prm.w1    = (const float*)d_in[27];
    prm.b1    = (const float*)d_in[28];
    prm.w2    = (const float*)d_in[29];
    prm.b2    = (const float*)d_in[30];
    prm.lnow  = (const float*)d_in[31];
    prm.lnob  = (const float*)d_in[32];
    prm.projw = (const float*)d_in[33];
    prm.projb = (const float*)d_in[34];
    prm.out   = (float*)d_out;
    prm.ws    = (float*)d_ws;
    prm.bar   = (unsigned*)d_ws;     // ws[0]; data buffers start at ws+64 floats

    // Query real co-residency and size the cooperative grid to fit.
    int dev = 0;
    (void)hipGetDevice(&dev);
    int numCU = 0;
    if (hipDeviceGetAttribute(&numCU, hipDeviceAttributeMultiprocessorCount, dev) != hipSuccess || numCU <= 0)
        numCU = 256;
    int maxB = 0;
    if (hipOccupancyMaxActiveBlocksPerMultiprocessor(&maxB, reinterpret_cast<const void*>(mega), 256, 0) != hipSuccess || maxB <= 0)
        maxB = 1;
    int grid = maxB * numCU;
    if (grid > 768) grid = 768;

    bar_init<<<1, 1, 0, stream>>>(prm.bar);
    void* args[] = { &prm };
    hipError_t e = hipLaunchCooperativeKernel(reinterpret_cast<void*>(mega),
                                              dim3(grid), dim3(256), args, 0, stream);
    if (e != hipSuccess) {
        (void)hipGetLastError();   // clear error state
        // Fallback: plain launch. grid <= co-resident capacity, so the
        // persistent-block barrier still completes; spin is bounded anyway.
        hipLaunchKernelGGL(mega, dim3(grid), dim3(256), 0, stream, prm);
    }
}

// Round 11
// 4547.838 us; speedup vs baseline: 1.6117x; 1.1539x over previous
//
#include <hip/hip_runtime.h>

#define BB 4
#define HH 20
#define DHD 64
#define DD 1280
#define DFFN 5120
#define VV 8000
#define HIST 1024
#define TENC 512
#define KVLEN 1025
#define NLAYER 16

static const size_t NK_OFF = 0;
static const size_t NV_OFF = 83968000ull;   // 16*4*20*64*1025
static const size_t LG_OFF = 167936000ull;
static const size_t KV_IDX = 167968000ull;

struct Prm {
    const float *kc, *vc, *ck, *cv;
    const int* ids;
    const float *mflag, *emb, *pe, *snw, *snb, *wq, *bq, *wk, *wv, *bv;
    const float *fcw, *fcb, *cnw, *cnb, *cwq, *cbq, *cfcw, *cfcb, *mnw, *mnb;
    const float *w1, *b1, *w2, *b2, *lnow, *lnob, *projw, *projb;
    float* out;
    float* ws;
    unsigned* bar;
};

__device__ __forceinline__ void fma4(float4& a, float s, const float4& w) {
    a.x += s * w.x; a.y += s * w.y; a.z += s * w.z; a.w += s * w.w;
}

// Device-coherent (agent-scope, sc1) scalar access for cross-block intermediates.
// These bypass the non-coherent per-XCD L2, so grid barriers need NO L2 wb/inv.
__device__ __forceinline__ float ld_coh(const float* p) {
    return __hip_atomic_load(p, __ATOMIC_RELAXED, __HIP_MEMORY_SCOPE_AGENT);
}
__device__ __forceinline__ void st_coh(float* p, float v) {
    __hip_atomic_store(p, v, __ATOMIC_RELAXED, __HIP_MEMORY_SCOPE_AGENT);
}

// Two-level tree barrier with fan-out release; monotonic epochs.
// Layout in bar[] (unsigned, 128B-strided to avoid line sharing):
//   leaf[i]  = bar[i*32],        i=0..31   (arrival counters)
//   root     = bar[1024]
//   rel[i]   = bar[1056 + i*32], i=0..31   (release flags, epoch values)
// Fence-free: all cross-block data uses sc1 accesses (visible at the device
// coherent point once retired); __syncthreads() + vmcnt drain precede arrival.
__device__ __forceinline__ void gsync(unsigned* bar, unsigned& r) {
    __syncthreads();
    if (threadIdx.x == 0) {
        asm volatile("s_waitcnt vmcnt(0) lgkmcnt(0)" ::: "memory");  // drain this wave's stores
        const unsigned leafCnt = gridDim.x >> 5;
        const unsigned leaf = blockIdx.x & 31;
        unsigned* lc   = bar + leaf * 32;
        unsigned* root = bar + 1024;
        unsigned* rel  = bar + 1056 + leaf * 32;
        bool released = false;
        unsigned old = __hip_atomic_fetch_add(lc, 1u, __ATOMIC_RELAXED, __HIP_MEMORY_SCOPE_AGENT);
        if (old == r * leafCnt - 1u) {                 // last arriver in this leaf
            unsigned ro = __hip_atomic_fetch_add(root, 1u, __ATOMIC_RELAXED, __HIP_MEMORY_SCOPE_AGENT);
            if (ro == r * 32u - 1u) {                  // global last: broadcast release
#pragma unroll
                for (int i = 0; i < 32; ++i)
                    __hip_atomic_store(bar + 1056 + i * 32, r, __ATOMIC_RELAXED, __HIP_MEMORY_SCOPE_AGENT);
                released = true;
            }
        }
        if (!released) {
            int slp = 1, polls = 0;
            while (__hip_atomic_load(rel, __ATOMIC_RELAXED, __HIP_MEMORY_SCOPE_AGENT) < r) {
                for (int s = 0; s < slp; ++s) __builtin_amdgcn_s_sleep(8);  // 512 cyc each
                if (slp < 8) slp <<= 1;            // cap 4096 cyc ≈ 1.7 µs
                if (++polls > (1 << 16)) break;    // bounded: degrade, never hang
            }
        }
    }
    __syncthreads();
    ++r;
}

__device__ __forceinline__ float blk_red_sum(float v, float* r4) {
#pragma unroll
    for (int o = 32; o; o >>= 1) v += __shfl_xor(v, o, 64);
    int w = threadIdx.x >> 6;
    __syncthreads();
    if ((threadIdx.x & 63) == 0) r4[w] = v;
    __syncthreads();
    return r4[0] + r4[1] + r4[2] + r4[3];
}

// x[b] += rbias + sum_j pin[j][b]; write x; xn[b] = LN(x)*lw+lb.  (block handles batch b)
__device__ void ln_micro(int b, float* x, const float* rbias, const float* pin, int np,
                         const float* lw, const float* lb, float* xn, float* r4) {
    int tid = threadIdx.x;
    float vloc[5]; float s = 0.f;
#pragma unroll
    for (int e = 0; e < 5; ++e) {
        int d = e * 256 + tid;
        float v = ld_coh(&x[b * DD + d]) + rbias[d];
        for (int j = 0; j < np; ++j) v += ld_coh(&pin[(size_t)(j * BB + b) * DD + d]);
        vloc[e] = v; s += v;
    }
#pragma unroll
    for (int e = 0; e < 5; ++e) st_coh(&x[b * DD + e * 256 + tid], vloc[e]);
    s = blk_red_sum(s, r4);
    float mean = s * (1.0f / DD);
    float sq = 0.f;
#pragma unroll
    for (int e = 0; e < 5; ++e) { float d0 = vloc[e] - mean; sq += d0 * d0; }
    sq = blk_red_sum(sq, r4);
    float rstd = rsqrtf(sq * (1.0f / DD) + 1e-5f);
#pragma unroll
    for (int e = 0; e < 5; ++e) {
        int d = e * 256 + tid;
        st_coh(&xn[b * DD + d], (vloc[e] - mean) * rstd * lw[d] + lb[d]);
    }
}

// GEMV core: acts am[4][rows] (LDS), W tile rows x 64 cols; coherent-writes outp.
__device__ __forceinline__ void gemv_core(const float* Wt, int ldw, int rows,
                                          const float* am, float* red,
                                          float* outp, int outN, int col0) {
    int tid = threadIdx.x, cl = tid & 15, sg = tid >> 4;
    float4 a0{0,0,0,0}, a1{0,0,0,0}, a2{0,0,0,0}, a3{0,0,0,0};
    const float* Wp = Wt + cl * 4;
    int iters = rows >> 4;
#pragma unroll 4
    for (int it = 0; it < iters; ++it) {
        int r = sg + it * 16;
        float4 w4 = *(const float4*)(Wp + (size_t)r * ldw);
        fma4(a0, am[r], w4);            fma4(a1, am[rows + r], w4);
        fma4(a2, am[2 * rows + r], w4); fma4(a3, am[3 * rows + r], w4);
    }
    int cq = cl * 4;
    float* rg = red + (size_t)(sg * 4) * 64;
    rg[cq] = a0.x; rg[cq+1] = a0.y; rg[cq+2] = a0.z; rg[cq+3] = a0.w;
    rg += 64; rg[cq] = a1.x; rg[cq+1] = a1.y; rg[cq+2] = a1.z; rg[cq+3] = a1.w;
    rg += 64; rg[cq] = a2.x; rg[cq+1] = a2.y; rg[cq+2] = a2.z; rg[cq+3] = a2.w;
    rg += 64; rg[cq] = a3.x; rg[cq+1] = a3.y; rg[cq+2] = a3.z; rg[cq+3] = a3.w;
    __syncthreads();
    int b = tid >> 6, c = tid & 63;
    float v = 0.f;
#pragma unroll
    for (int g = 0; g < 16; ++g) v += red[(size_t)(g * 4 + b) * 64 + c];
    st_coh(&outp[(size_t)b * outN + col0 + c], v);
}

__global__ void bar_init(unsigned* bar) {
    for (int i = threadIdx.x; i < 4096; i += 256) bar[i] = 0u;
}

__global__ __launch_bounds__(256, 3) void mega(Prm p) {
    __shared__ float sm[5376];        // 21.5 KB: red[4096] | am[1280]
    float* red = sm;
    float* am  = sm + 4096;
    // attention aliases (inside red region; phases barrier-separated)
    float* qs    = sm;          // 64
    float* knS   = sm + 64;     // 64
    float* vnS   = sm + 128;    // 64
    float* sc8   = sm + 192;    // [8][128]
    float* parr  = sm + 1216;   // 128
    float* redA  = sm + 1344;   // 128
    float* pvred = sm + 1472;   // [16][64]
    float* snS   = sm + 2496;   // 1

    const int bid = blockIdx.x, tid = threadIdx.x;
    const int G = gridDim.x;
    unsigned r = 1;

    float* x      = p.ws + 4096;
    float* xn     = p.ws + 9216;
    float* qkvp   = p.ws + 14336;    // [24][20][4][64] = 122880
    float* selfS  = p.ws + 137216;   // [4*20*8]*66 = 42240
    float* crossS = p.ws + 179456;   // [4*20*4]*66 = 21120
    float* fcP    = p.ws + 200576;   // [16*4][1280] = 81920
    float* cfcP   = p.ws + 282496;   // 81920
    float* f1P    = p.ws + 364416;   // [8*4][5120] = 163840
    float* ff2P   = p.ws + 528256;   // [16*4][1280] = 81920
    float* projP  = p.ws + 610176;   // [4*4][8000] = 128000

    float* nk = p.out + NK_OFF;
    float* nv = p.out + NV_OFF;
    const float flag = p.mflag[0];

    // ---- P0: embed + LN0 ----
    if (bid < BB) {
        int b = bid, tok = p.ids[b];
        float vloc[5]; float s = 0.f;
#pragma unroll
        for (int e = 0; e < 5; ++e) {
            int d = e * 256 + tid;
            float v = p.emb[(size_t)tok * DD + d] + p.pe[(size_t)HIST * DD + d];
            vloc[e] = v; s += v;
            st_coh(&x[b * DD + d], v);
        }
        s = blk_red_sum(s, sm);
        float mean = s * (1.0f / DD);
        float sq = 0.f;
#pragma unroll
        for (int e = 0; e < 5; ++e) { float d0 = vloc[e] - mean; sq += d0 * d0; }
        sq = blk_red_sum(sq, sm);
        float rstd = rsqrtf(sq * (1.0f / DD) + 1e-5f);
#pragma unroll
        for (int e = 0; e < 5; ++e) {
            int d = e * 256 + tid;
            st_coh(&xn[b * DD + d], (vloc[e] - mean) * rstd * p.snw[d] + p.snb[d]);
        }
    }
    gsync(p.bar, r);

    for (int l = 0; l < NLAYER; ++l) {
        const float* kc_l  = p.kc  + (size_t)l * 5242880;
        const float* vc_l  = p.vc  + (size_t)l * 5242880;
        const float* ck_l  = p.ck  + (size_t)l * 2621440;
        const float* cv_l  = p.cv  + (size_t)l * 2621440;
        float* nk_l = nk + (size_t)l * 5248000;
        float* nv_l = nv + (size_t)l * 5248000;
        const float* wq_l   = p.wq   + (size_t)l * 1638400;
        const float* wk_l   = p.wk   + (size_t)l * 1638400;
        const float* wv_l   = p.wv   + (size_t)l * 1638400;
        const float* cwq_l  = p.cwq  + (size_t)l * 1638400;
        const float* fcw_l  = p.fcw  + (size_t)l * 1638400;
        const float* cfcw_l = p.cfcw + (size_t)l * 1638400;
        const float* bq_l   = p.bq   + (size_t)l * 1280;
        const float* bv_l   = p.bv   + (size_t)l * 1280;
        const float* cbq_l  = p.cbq  + (size_t)l * 1280;
        const float* fcb_l  = p.fcb  + (size_t)l * DD;
        const float* cfcb_l = p.cfcb + (size_t)l * DD;
        const float* w1_l   = p.w1   + (size_t)l * 6553600;
        const float* b1_l   = p.b1   + (size_t)l * DFFN;
        const float* w2_l   = p.w2   + (size_t)l * 6553600;
        const float* b2_l   = p.b2   + (size_t)l * DD;

        // ---- P1: self QKV, 480 units = (mat*20+h)*8 + rc, rows=160 ----
        for (int u = bid; u < 480; u += G) {
            int rc = u & 7, mh = u >> 3, h = mh % 20, mat = mh / 20;
            const float* W = (mat == 0 ? wq_l : mat == 1 ? wk_l : wv_l)
                           + (size_t)h * 81920 + (size_t)rc * 160 * 64;
            for (int i = tid; i < 640; i += 256)
                am[i] = ld_coh(&xn[(i / 160) * DD + rc * 160 + (i % 160)]);
            __syncthreads();
            gemv_core(W, 64, 160, am, red,
                      qkvp + (size_t)((mat * 8 + rc) * HH + h) * BB * 64, 64, 0);
            __syncthreads();
        }
        gsync(p.bar, r);

        // ---- P2: self-attention, 640 units = ((h*4+b)*8)+c, chunk=128 ----
        for (int u = bid; u < 640; u += G) {
            int c = u & 7, hb = u >> 3, b = hb & 3, h = hb >> 2;
            if (tid < 64) {
                float qv = bq_l[h * 64 + tid];
#pragma unroll
                for (int j = 0; j < 8; ++j)
                    qv += ld_coh(&qkvp[(size_t)((j * HH + h) * BB + b) * 64 + tid]);
                qs[tid] = qv;
            } else if (tid < 128 && c == 0) {
                int t2 = tid - 64;
                float kn = 0.f;
#pragma unroll
                for (int j = 0; j < 8; ++j)
                    kn += ld_coh(&qkvp[(size_t)(((8 + j) * HH + h) * BB + b) * 64 + t2]);
                knS[t2] = kn;
                nk_l[((size_t)(b * HH + h) * 64 + t2) * KVLEN + HIST] = kn;
            } else if (tid < 192 && c == 0) {
                int t2 = tid - 128;
                float vn = bv_l[h * 64 + t2];
#pragma unroll
                for (int j = 0; j < 8; ++j)
                    vn += ld_coh(&qkvp[(size_t)(((16 + j) * HH + h) * BB + b) * 64 + t2]);
                vnS[t2] = vn;
                nv_l[(size_t)(b * HH + h) * KVLEN * 64 + (size_t)HIST * 64 + t2] = vn;
            }
            __syncthreads();
            // K phase
            int clK = tid & 31, gK = tid >> 5;
            int jb = c * 128 + clK * 4;
            const float* kb = kc_l + (size_t)(b * HH + h) * 64 * HIST;
            float* nkb = nk_l + (size_t)(b * HH + h) * 64 * KVLEN;
            float ax = 0, ay = 0, az = 0, aw = 0;
#pragma unroll
            for (int it = 0; it < 8; ++it) {
                int dh = gK * 8 + it;
                float4 k4 = *(const float4*)(kb + (size_t)dh * HIST + jb);
                float* nr = nkb + (size_t)dh * KVLEN + jb;
                nr[0] = k4.x; nr[1] = k4.y; nr[2] = k4.z; nr[3] = k4.w;
                float qd = qs[dh];
                ax += qd * k4.x; ay += qd * k4.y; az += qd * k4.z; aw += qd * k4.w;
            }
            sc8[gK * 128 + clK * 4 + 0] = ax; sc8[gK * 128 + clK * 4 + 1] = ay;
            sc8[gK * 128 + clK * 4 + 2] = az; sc8[gK * 128 + clK * 4 + 3] = aw;
            __syncthreads();
            float s = 0.f;
            if (tid < 128) {
#pragma unroll
                for (int g = 0; g < 8; ++g) s += sc8[g * 128 + tid];
                int j = c * 128 + tid;
                if (j != 0) s += -128.0f * flag;
            }
            if (c == 0 && tid < 64) {
                float pp = qs[tid] * knS[tid];
#pragma unroll
                for (int o = 32; o; o >>= 1) pp += __shfl_xor(pp, o, 64);
                if (tid == 0) snS[0] = pp + (-128.0f * flag);
            }
            if (tid < 128) redA[tid] = s;
            __syncthreads();
            for (int st = 64; st; st >>= 1) {
                if (tid < st) redA[tid] = fmaxf(redA[tid], redA[tid + st]);
                __syncthreads();
            }
            float m = redA[0];
            if (c == 0) m = fmaxf(m, snS[0]);
            __syncthreads();
            float pp = 0.f;
            if (tid < 128) { pp = expf(s - m); parr[tid] = pp; redA[tid] = pp; }
            __syncthreads();
            for (int st = 64; st; st >>= 1) {
                if (tid < st) redA[tid] += redA[tid + st];
                __syncthreads();
            }
            float ssum = redA[0];
            float en = (c == 0) ? expf(snS[0] - m) : 0.0f;
            // V phase
            int clV = tid & 15, rg = tid >> 4;
            const float* vb = vc_l + (size_t)(b * HH + h) * HIST * 64;
            float* nvb = nv_l + (size_t)(b * HH + h) * KVLEN * 64;
            float vx = 0, vy = 0, vz = 0, vw = 0;
#pragma unroll
            for (int it = 0; it < 8; ++it) {
                int i = rg * 8 + it;
                size_t jj = (size_t)(c * 128 + i);
                float4 v4 = *(const float4*)(vb + jj * 64 + clV * 4);
                *(float4*)(nvb + jj * 64 + clV * 4) = v4;
                float pw = parr[i];
                vx += pw * v4.x; vy += pw * v4.y; vz += pw * v4.z; vw += pw * v4.w;
            }
            pvred[rg * 64 + clV * 4 + 0] = vx; pvred[rg * 64 + clV * 4 + 1] = vy;
            pvred[rg * 64 + clV * 4 + 2] = vz; pvred[rg * 64 + clV * 4 + 3] = vw;
            __syncthreads();
            float* st_ = selfS + (size_t)((b * HH + h) * 8 + c) * 66;
            if (tid == 0) {
                st_coh(&st_[0], m); st_coh(&st_[1], ssum + en);
            }
            if (tid < 64) {
                float pv = 0.f;
#pragma unroll
                for (int rgi = 0; rgi < 16; ++rgi) pv += pvred[rgi * 64 + tid];
                if (c == 0) pv += en * vnS[tid];
                st_coh(&st_[2 + tid], pv);
            }
            __syncthreads();
        }
        gsync(p.bar, r);

        // ---- P3: fc out-proj, 320 units = rc*20+cc, rows=80, merge selfS(8) ----
        for (int u = bid; u < 320; u += G) {
            int cc = u % 20, rcx = u / 20, row0 = rcx * 80;
            for (int i = tid; i < 320; i += 256) {
                int b = i / 80, rr = i % 80, gr = row0 + rr, hh = gr >> 6, dh = gr & 63;
                const float* st = selfS + (size_t)((b * HH + hh) * 8) * 66;
                float M = ld_coh(&st[0]);
#pragma unroll
                for (int ci = 1; ci < 8; ++ci) M = fmaxf(M, ld_coh(&st[ci * 66]));
                float den = 0.f, num = 0.f;
#pragma unroll
                for (int ci = 0; ci < 8; ++ci) {
                    float e = expf(ld_coh(&st[ci * 66]) - M);
                    den += e * ld_coh(&st[ci * 66 + 1]);
                    num += e * ld_coh(&st[ci * 66 + 2 + dh]);
                }
                am[b * 80 + rr] = num / den;
            }
            __syncthreads();
            gemv_core(fcw_l + (size_t)row0 * DD + cc * 64, DD, 80, am, red,
                      fcP + (size_t)(rcx * BB) * DD, DD, cc * 64);
            __syncthreads();
        }
        gsync(p.bar, r);

        // ---- P4: LN1 ----
        if (bid < BB) ln_micro(bid, x, fcb_l, fcP, 16, p.cnw + l * DD, p.cnb + l * DD, xn, sm);
        gsync(p.bar, r);

        // ---- P5: cross Q, 160 units = h*8+rc, rows=160 ----
        for (int u = bid; u < 160; u += G) {
            int rc = u & 7, h = u >> 3;
            const float* W = cwq_l + (size_t)h * 81920 + (size_t)rc * 160 * 64;
            for (int i = tid; i < 640; i += 256)
                am[i] = ld_coh(&xn[(i / 160) * DD + rc * 160 + (i % 160)]);
            __syncthreads();
            gemv_core(W, 64, 160, am, red,
                      qkvp + (size_t)(rc * HH + h) * BB * 64, 64, 0);
            __syncthreads();
        }
        gsync(p.bar, r);

        // ---- P6: cross-attention, 320 units = ((h*4+b)*4)+c, chunk=128 ----
        for (int u = bid; u < 320; u += G) {
            int c = u & 3, hb = u >> 2, b = hb & 3, h = hb >> 2;
            if (tid < 64) {
                float qv = cbq_l[h * 64 + tid];
#pragma unroll
                for (int j = 0; j < 8; ++j)
                    qv += ld_coh(&qkvp[(size_t)((j * HH + h) * BB + b) * 64 + tid]);
                qs[tid] = qv;
            }
            __syncthreads();
            int clK = tid & 31, gK = tid >> 5;
            int jb = c * 128 + clK * 4;
            const float* kb = ck_l + (size_t)(b * HH + h) * 64 * TENC;
            float ax = 0, ay = 0, az = 0, aw = 0;
#pragma unroll
            for (int it = 0; it < 8; ++it) {
                int dh = gK * 8 + it;
                float4 k4 = *(const float4*)(kb + (size_t)dh * TENC + jb);
                float qd = qs[dh];
                ax += qd * k4.x; ay += qd * k4.y; az += qd * k4.z; aw += qd * k4.w;
            }
            sc8[gK * 128 + clK * 4 + 0] = ax; sc8[gK * 128 + clK * 4 + 1] = ay;
            sc8[gK * 128 + clK * 4 + 2] = az; sc8[gK * 128 + clK * 4 + 3] = aw;
            __syncthreads();
            float s = 0.f;
            if (tid < 128) {
#pragma unroll
                for (int g = 0; g < 8; ++g) s += sc8[g * 128 + tid];
            }
            if (tid < 128) redA[tid] = s;
            __syncthreads();
            for (int st = 64; st; st >>= 1) {
                if (tid < st) redA[tid] = fmaxf(redA[tid], redA[tid + st]);
                __syncthreads();
            }
            float m = redA[0];
            __syncthreads();
            float pp = 0.f;
            if (tid < 128) { pp = expf(s - m); parr[tid] = pp; redA[tid] = pp; }
            __syncthreads();
            for (int st = 64; st; st >>= 1) {
                if (tid < st) redA[tid] += redA[tid + st];
                __syncthreads();
            }
            float ssum = redA[0];
            int clV = tid & 15, rg = tid >> 4;
            const float* vb = cv_l + (size_t)(b * HH + h) * TENC * 64;
            float vx = 0, vy = 0, vz = 0, vw = 0;
#pragma unroll
            for (int it = 0; it < 8; ++it) {
                int i = rg * 8 + it;
                size_t jj = (size_t)(c * 128 + i);
                float4 v4 = *(const float4*)(vb + jj * 64 + clV * 4);
                float pw = parr[i];
                vx += pw * v4.x; vy += pw * v4.y; vz += pw * v4.z; vw += pw * v4.w;
            }
            pvred[rg * 64 + clV * 4 + 0] = vx; pvred[rg * 64 + clV * 4 + 1] = vy;
            pvred[rg * 64 + clV * 4 + 2] = vz; pvred[rg * 64 + clV * 4 + 3] = vw;
            __syncthreads();
            float* st_ = crossS + (size_t)((b * HH + h) * 4 + c) * 66;
            if (tid == 0) { st_coh(&st_[0], m); st_coh(&st_[1], ssum); }
            if (tid < 64) {
                float pv = 0.f;
#pragma unroll
                for (int rgi = 0; rgi < 16; ++rgi) pv += pvred[rgi * 64 + tid];
                st_coh(&st_[2 + tid], pv);
            }
            __syncthreads();
        }
        gsync(p.bar, r);

        // ---- P7: cfc out-proj, 320 units, merge crossS(4) ----
        for (int u = bid; u < 320; u += G) {
            int cc = u % 20, rcx = u / 20, row0 = rcx * 80;
            for (int i = tid; i < 320; i += 256) {
                int b = i / 80, rr = i % 80, gr = row0 + rr, hh = gr >> 6, dh = gr & 63;
                const float* st = crossS + (size_t)((b * HH + hh) * 4) * 66;
                float M = ld_coh(&st[0]);
#pragma unroll
                for (int ci = 1; ci < 4; ++ci) M = fmaxf(M, ld_coh(&st[ci * 66]));
                float den = 0.f, num = 0.f;
#pragma unroll
                for (int ci = 0; ci < 4; ++ci) {
                    float e = expf(ld_coh(&st[ci * 66]) - M);
                    den += e * ld_coh(&st[ci * 66 + 1]);
                    num += e * ld_coh(&st[ci * 66 + 2 + dh]);
                }
                am[b * 80 + rr] = num / den;
            }
            __syncthreads();
            gemv_core(cfcw_l + (size_t)row0 * DD + cc * 64, DD, 80, am, red,
                      cfcP + (size_t)(rcx * BB) * DD, DD, cc * 64);
            __syncthreads();
        }
        gsync(p.bar, r);

        // ---- P8: LN2 ----
        if (bid < BB) ln_micro(bid, x, cfcb_l, cfcP, 16, p.mnw + l * DD, p.mnb + l * DD, xn, sm);
        gsync(p.bar, r);

        // ---- P9: FFN1, 640 units = rc*80+cc, rows=160 ----
        for (int u = bid; u < 640; u += G) {
            int cc = u % 80, rcx = u / 80, row0 = rcx * 160;
            for (int i = tid; i < 640; i += 256)
                am[i] = ld_coh(&xn[(i / 160) * DD + row0 + (i % 160)]);
            __syncthreads();
            gemv_core(w1_l + (size_t)row0 * DFFN + cc * 64, DFFN, 160, am, red,
                      f1P + (size_t)(rcx * BB) * DFFN, DFFN, cc * 64);
            __syncthreads();
        }
        gsync(p.bar, r);

        // ---- P10: FFN2, 320 units = rc*20+cc, rows=320, relu-merge f1P(8) ----
        for (int u = bid; u < 320; u += G) {
            int cc = u % 20, rcx = u / 20, row0 = rcx * 320;
            for (int i = tid; i < 1280; i += 256) {
                int b = i / 320, rr = i % 320;
                float v = b1_l[row0 + rr];
#pragma unroll
                for (int j = 0; j < 8; ++j)
                    v += ld_coh(&f1P[(size_t)(j * BB + b) * DFFN + row0 + rr]);
                am[i] = fmaxf(v, 0.0f);
            }
            __syncthreads();
            gemv_core(w2_l + (size_t)row0 * DD + cc * 64, DD, 320, am, red,
                      ff2P + (size_t)(rcx * BB) * DD, DD, cc * 64);
            __syncthreads();
        }
        gsync(p.bar, r);

        // ---- P11: LN3 (next layer's snw/snb, or final lnow/lnob) ----
        if (bid < BB) {
            const float* nlw = (l < NLAYER - 1) ? p.snw + (l + 1) * DD : p.lnow;
            const float* nlb = (l < NLAYER - 1) ? p.snb + (l + 1) * DD : p.lnob;
            ln_micro(bid, x, b2_l, ff2P, 16, nlw, nlb, xn, sm);
        }
        gsync(p.bar, r);
    }

    // ---- P12: final projection, 500 units = rc*125+cc, rows=320 ----
    for (int u = bid; u < 500; u += G) {
        int cc = u % 125, rcx = u / 125, row0 = rcx * 320;
        for (int i = tid; i < 1280; i += 256)
            am[i] = ld_coh(&xn[(i / 320) * DD + row0 + (i % 320)]);
        __syncthreads();
        gemv_core(p.projw + (size_t)row0 * VV + cc * 64, VV, 320, am, red,
                  projP + (size_t)(rcx * BB) * VV, VV, cc * 64);
        __syncthreads();
    }
    gsync(p.bar, r);

    // ---- P13: logits finalize + kv scalar ----
    for (int u = bid; u < 125; u += G) {
        int b = tid >> 6, c = u * 64 + (tid & 63);
        float v = p.projb[c];
#pragma unroll
        for (int j = 0; j < 4; ++j) v += ld_coh(&projP[(size_t)(j * BB + b) * VV + c]);
        p.out[LG_OFF + (size_t)b * VV + c] = v;
    }
    if (bid == 0 && tid == 0) p.out[KV_IDX] = (float)(HIST + 1);
}

// ---------------- host ----------------
extern "C" void kernel_launch(void* const* d_in, const int* in_sizes, int n_in,
                              void* d_out, int out_size, void* d_ws, size_t ws_size,
                              hipStream_t stream) {
    Prm prm;
    prm.kc    = (const float*)d_in[0];
    prm.vc    = (const float*)d_in[1];
    prm.ck    = (const float*)d_in[2];
    prm.cv    = (const float*)d_in[3];
    prm.ids   = (const int*)d_in[4];
    prm.mflag = (const float*)d_in[7];
    prm.emb   = (const float*)d_in[8];
    prm.pe    = (const float*)d_in[9];
    prm.snw   = (const float*)d_in[10];
    prm.snb   = (const float*)d_in[11];
    prm.wq    = (const float*)d_in[12];
    prm.bq    = (const float*)d_in[13];
    prm.wk    = (const float*)d_in[14];
    prm.wv    = (const float*)d_in[15];
    prm.bv    = (const float*)d_in[16];
    prm.fcw   = (const float*)d_in[17];
    prm.fcb   = (const float*)d_in[18];
    prm.cnw   = (const float*)d_in[19];
    prm.cnb   = (const float*)d_in[20];
    prm.cwq   = (const float*)d_in[21];
    prm.cbq   = (const float*)d_in[22];
    prm.cfcw  = (const float*)d_in[23];
    prm.cfcb  = (const float*)d_in[24];
    prm.mnw   = (const float*)d_in[25];
    prm.mnb   = (const float*)d_in[26];
    prm.w1    = (const float*)d_in[27];
    prm.b1    = (const float*)d_in[28];
    prm.w2    = (const float*)d_in[29];
    prm.b2    = (const float*)d_in[30];
    prm.lnow  = (const float*)d_in[31];
    prm.lnob  = (const float*)d_in[32];
    prm.projw = (const float*)d_in[33];
    prm.projb = (const float*)d_in[34];
    prm.out   = (float*)d_out;
    prm.ws    = (float*)d_ws;
    prm.bar   = (unsigned*)d_ws;     // bar[0..4095]; data buffers start at ws+4096 floats

    // Query real co-residency and size the cooperative grid to fit (multiple of 32).
    int dev = 0;
    (void)hipGetDevice(&dev);
    int numCU = 0;
    if (hipDeviceGetAttribute(&numCU, hipDeviceAttributeMultiprocessorCount, dev) != hipSuccess || numCU <= 0)
        numCU = 256;
    int maxB = 0;
    if (hipOccupancyMaxActiveBlocksPerMultiprocessor(&maxB, reinterpret_cast<const void*>(mega), 256, 0) != hipSuccess || maxB <= 0)
        maxB = 1;
    int grid = maxB * numCU;
    if (grid > 768) grid = 768;
    grid &= ~31;
    if (grid < 32) grid = 32;

    bar_init<<<1, 256, 0, stream>>>(prm.bar);
    void* args[] = { &prm };
    hipError_t e = hipLaunchCooperativeKernel(reinterpret_cast<void*>(mega),
                                              dim3(grid), dim3(256), args, 0, stream);
    if (e != hipSuccess) {
        (void)hipGetLastError();   // clear error state
        // Fallback: plain launch. grid <= co-resident capacity, so the
        // persistent-block barrier still completes; spin is bounded anyway.
        hipLaunchKernelGGL(mega, dim3(grid), dim3(256), 0, stream, prm);
    }
}

// Round 12
// 3600.710 us; speedup vs baseline: 2.0357x; 1.2630x over previous
//
#include <hip/hip_runtime.h>

#define BB 4
#define HH 20
#define DHD 64
#define DD 1280
#define DFFN 5120
#define VV 8000
#define HIST 1024
#define TENC 512
#define KVLEN 1025
#define NLAYER 16

static const size_t NK_OFF = 0;
static const size_t NV_OFF = 83968000ull;   // 16*4*20*64*1025
static const size_t LG_OFF = 167936000ull;
static const size_t KV_IDX = 167968000ull;

struct Prm {
    const float *kc, *vc, *ck, *cv;
    const int* ids;
    const float *mflag, *emb, *pe, *snw, *snb, *wq, *bq, *wk, *wv, *bv;
    const float *fcw, *fcb, *cnw, *cnb, *cwq, *cbq, *cfcw, *cfcb, *mnw, *mnb;
    const float *w1, *b1, *w2, *b2, *lnow, *lnob, *projw, *projb;
    float* out;
    float* ws;
    unsigned* bar;
};

__device__ __forceinline__ void fma4(float4& a, float s, const float4& w) {
    a.x += s * w.x; a.y += s * w.y; a.z += s * w.z; a.w += s * w.w;
}

// Device-coherent (agent-scope, sc1) scalar access for cross-block intermediates.
// These bypass the non-coherent per-XCD L2, so grid barriers need NO L2 wb/inv.
__device__ __forceinline__ float ld_coh(const float* p) {
    return __hip_atomic_load(p, __ATOMIC_RELAXED, __HIP_MEMORY_SCOPE_AGENT);
}
__device__ __forceinline__ void st_coh(float* p, float v) {
    __hip_atomic_store(p, v, __ATOMIC_RELAXED, __HIP_MEMORY_SCOPE_AGENT);
}

// Two-level tree barrier with fan-out release; monotonic epochs.
// bar layout: leaf[i]=bar[i*32] (i<32), root=bar[1024], rel[i]=bar[1056+i*32].
// Fence-free: cross-block data uses sc1 accesses; __syncthreads() + vmcnt drain
// precede arrival.
__device__ __forceinline__ void gsync(unsigned* bar, unsigned& r) {
    __syncthreads();
    if (threadIdx.x == 0) {
        asm volatile("s_waitcnt vmcnt(0) lgkmcnt(0)" ::: "memory");
        const unsigned leafCnt = gridDim.x >> 5;
        const unsigned leaf = blockIdx.x & 31;
        unsigned* lc   = bar + leaf * 32;
        unsigned* root = bar + 1024;
        unsigned* rel  = bar + 1056 + leaf * 32;
        bool released = false;
        unsigned old = __hip_atomic_fetch_add(lc, 1u, __ATOMIC_RELAXED, __HIP_MEMORY_SCOPE_AGENT);
        if (old == r * leafCnt - 1u) {
            unsigned ro = __hip_atomic_fetch_add(root, 1u, __ATOMIC_RELAXED, __HIP_MEMORY_SCOPE_AGENT);
            if (ro == r * 32u - 1u) {
#pragma unroll
                for (int i = 0; i < 32; ++i)
                    __hip_atomic_store(bar + 1056 + i * 32, r, __ATOMIC_RELAXED, __HIP_MEMORY_SCOPE_AGENT);
                released = true;
            }
        }
        if (!released) {
            int slp = 1, polls = 0;
            while (__hip_atomic_load(rel, __ATOMIC_RELAXED, __HIP_MEMORY_SCOPE_AGENT) < r) {
                for (int s = 0; s < slp; ++s) __builtin_amdgcn_s_sleep(8);  // 512 cyc each
                if (slp < 4) slp <<= 1;            // cap 2048 cyc ~ 0.85 us
                if (++polls > (1 << 16)) break;    // bounded: degrade, never hang
            }
        }
    }
    __syncthreads();
    ++r;
}

__device__ __forceinline__ float blk_red_sum(float v, float* r4) {
#pragma unroll
    for (int o = 32; o; o >>= 1) v += __shfl_xor(v, o, 64);
    int w = threadIdx.x >> 6;
    __syncthreads();
    if ((threadIdx.x & 63) == 0) r4[w] = v;
    __syncthreads();
    return r4[0] + r4[1] + r4[2] + r4[3];
}

// x[b] += rbias + sum_j pin[j][b]; write x; xn[b] = LN(x)*lw+lb.  (block handles batch b)
// NP is compile-time so the sc1 partial loads are issued back-to-back (one waitcnt),
// not load->wait->add serialized (that was ~60us/phase at runtime np).
template <int NP>
__device__ void ln_micro(int b, float* x, const float* rbias, const float* pin,
                         const float* lw, const float* lb, float* xn, float* r4) {
    int tid = threadIdx.x;
    float vloc[5]; float s = 0.f;
#pragma unroll
    for (int e = 0; e < 5; ++e) {
        int d = e * 256 + tid;
        float pv[NP];
#pragma unroll
        for (int j = 0; j < NP; ++j)
            pv[j] = ld_coh(&pin[(size_t)(j * BB + b) * DD + d]);
        float v = ld_coh(&x[b * DD + d]) + rbias[d];
#pragma unroll
        for (int j = 0; j < NP; ++j) v += pv[j];
        vloc[e] = v; s += v;
    }
#pragma unroll
    for (int e = 0; e < 5; ++e) st_coh(&x[b * DD + e * 256 + tid], vloc[e]);
    s = blk_red_sum(s, r4);
    float mean = s * (1.0f / DD);
    float sq = 0.f;
#pragma unroll
    for (int e = 0; e < 5; ++e) { float d0 = vloc[e] - mean; sq += d0 * d0; }
    sq = blk_red_sum(sq, r4);
    float rstd = rsqrtf(sq * (1.0f / DD) + 1e-5f);
#pragma unroll
    for (int e = 0; e < 5; ++e) {
        int d = e * 256 + tid;
        st_coh(&xn[b * DD + d], (vloc[e] - mean) * rstd * lw[d] + lb[d]);
    }
}

// GEMV core: acts am[4][rows] (LDS), W tile rows x 64 cols; coherent-writes outp.
__device__ __forceinline__ void gemv_core(const float* Wt, int ldw, int rows,
                                          const float* am, float* red,
                                          float* outp, int outN, int col0) {
    int tid = threadIdx.x, cl = tid & 15, sg = tid >> 4;
    float4 a0{0,0,0,0}, a1{0,0,0,0}, a2{0,0,0,0}, a3{0,0,0,0};
    const float* Wp = Wt + cl * 4;
    int iters = rows >> 4;
#pragma unroll 4
    for (int it = 0; it < iters; ++it) {
        int r = sg + it * 16;
        float4 w4 = *(const float4*)(Wp + (size_t)r * ldw);
        fma4(a0, am[r], w4);            fma4(a1, am[rows + r], w4);
        fma4(a2, am[2 * rows + r], w4); fma4(a3, am[3 * rows + r], w4);
    }
    int cq = cl * 4;
    float* rg = red + (size_t)(sg * 4) * 64;
    rg[cq] = a0.x; rg[cq+1] = a0.y; rg[cq+2] = a0.z; rg[cq+3] = a0.w;
    rg += 64; rg[cq] = a1.x; rg[cq+1] = a1.y; rg[cq+2] = a1.z; rg[cq+3] = a1.w;
    rg += 64; rg[cq] = a2.x; rg[cq+1] = a2.y; rg[cq+2] = a2.z; rg[cq+3] = a2.w;
    rg += 64; rg[cq] = a3.x; rg[cq+1] = a3.y; rg[cq+2] = a3.z; rg[cq+3] = a3.w;
    __syncthreads();
    int b = tid >> 6, c = tid & 63;
    float v = 0.f;
#pragma unroll
    for (int g = 0; g < 16; ++g) v += red[(size_t)(g * 4 + b) * 64 + c];
    st_coh(&outp[(size_t)b * outN + col0 + c], v);
}

__global__ void bar_init(unsigned* bar) {
    for (int i = threadIdx.x; i < 4096; i += 256) bar[i] = 0u;
}

__global__ __launch_bounds__(256, 3) void mega(Prm p) {
    __shared__ float sm[5376];        // 21.5 KB: red[4096] | am[1280]
    float* red = sm;
    float* am  = sm + 4096;
    // attention aliases (inside red region; phases barrier-separated)
    float* qs    = sm;          // 64
    float* knS   = sm + 64;     // 64
    float* vnS   = sm + 128;    // 64
    float* sc8   = sm + 192;    // [8][128]
    float* parr  = sm + 1216;   // 128
    float* redA  = sm + 1344;   // 128
    float* pvred = sm + 1472;   // [16][64]
    float* snS   = sm + 2496;   // 1

    const int bid = blockIdx.x, tid = threadIdx.x;
    const int G = gridDim.x;
    unsigned r = 1;

    float* x      = p.ws + 4096;
    float* xn     = p.ws + 9216;
    float* qkvp   = p.ws + 14336;    // [24][20][4][64] = 122880
    float* selfS  = p.ws + 137216;   // [4*20*8]*66 = 42240
    float* crossS = p.ws + 179456;   // [4*20*4]*66 = 21120
    float* fcP    = p.ws + 200576;   // [16*4][1280] = 81920
    float* cfcP   = p.ws + 282496;   // 81920
    float* f1P    = p.ws + 364416;   // [8*4][5120] = 163840
    float* ff2P   = p.ws + 528256;   // [16*4][1280] = 81920
    float* projP  = p.ws + 610176;   // [4*4][8000] = 128000

    float* nk = p.out + NK_OFF;
    float* nv = p.out + NV_OFF;
    const float flag = p.mflag[0];

    // ---- P0: embed + LN0 ----
    if (bid < BB) {
        int b = bid, tok = p.ids[b];
        float vloc[5]; float s = 0.f;
#pragma unroll
        for (int e = 0; e < 5; ++e) {
            int d = e * 256 + tid;
            float v = p.emb[(size_t)tok * DD + d] + p.pe[(size_t)HIST * DD + d];
            vloc[e] = v; s += v;
            st_coh(&x[b * DD + d], v);
        }
        s = blk_red_sum(s, sm);
        float mean = s * (1.0f / DD);
        float sq = 0.f;
#pragma unroll
        for (int e = 0; e < 5; ++e) { float d0 = vloc[e] - mean; sq += d0 * d0; }
        sq = blk_red_sum(sq, sm);
        float rstd = rsqrtf(sq * (1.0f / DD) + 1e-5f);
#pragma unroll
        for (int e = 0; e < 5; ++e) {
            int d = e * 256 + tid;
            st_coh(&xn[b * DD + d], (vloc[e] - mean) * rstd * p.snw[d] + p.snb[d]);
        }
    }
    gsync(p.bar, r);

    for (int l = 0; l < NLAYER; ++l) {
        const float* kc_l  = p.kc  + (size_t)l * 5242880;
        const float* vc_l  = p.vc  + (size_t)l * 5242880;
        const float* ck_l  = p.ck  + (size_t)l * 2621440;
        const float* cv_l  = p.cv  + (size_t)l * 2621440;
        float* nk_l = nk + (size_t)l * 5248000;
        float* nv_l = nv + (size_t)l * 5248000;
        const float* wq_l   = p.wq   + (size_t)l * 1638400;
        const float* wk_l   = p.wk   + (size_t)l * 1638400;
        const float* wv_l   = p.wv   + (size_t)l * 1638400;
        const float* cwq_l  = p.cwq  + (size_t)l * 1638400;
        const float* fcw_l  = p.fcw  + (size_t)l * 1638400;
        const float* cfcw_l = p.cfcw + (size_t)l * 1638400;
        const float* bq_l   = p.bq   + (size_t)l * 1280;
        const float* bv_l   = p.bv   + (size_t)l * 1280;
        const float* cbq_l  = p.cbq  + (size_t)l * 1280;
        const float* fcb_l  = p.fcb  + (size_t)l * DD;
        const float* cfcb_l = p.cfcb + (size_t)l * DD;
        const float* w1_l   = p.w1   + (size_t)l * 6553600;
        const float* b1_l   = p.b1   + (size_t)l * DFFN;
        const float* w2_l   = p.w2   + (size_t)l * 6553600;
        const float* b2_l   = p.b2   + (size_t)l * DD;

        // ---- P1: self QKV, 480 units = (mat*20+h)*8 + rc, rows=160 ----
        for (int u = bid; u < 480; u += G) {
            int rc = u & 7, mh = u >> 3, h = mh % 20, mat = mh / 20;
            const float* W = (mat == 0 ? wq_l : mat == 1 ? wk_l : wv_l)
                           + (size_t)h * 81920 + (size_t)rc * 160 * 64;
            for (int i = tid; i < 640; i += 256)
                am[i] = ld_coh(&xn[(i / 160) * DD + rc * 160 + (i % 160)]);
            __syncthreads();
            gemv_core(W, 64, 160, am, red,
                      qkvp + (size_t)((mat * 8 + rc) * HH + h) * BB * 64, 64, 0);
            __syncthreads();
        }
        gsync(p.bar, r);

        // ---- P2: self-attention, 640 units = ((h*4+b)*8)+c, chunk=128 ----
        for (int u = bid; u < 640; u += G) {
            int c = u & 7, hb = u >> 3, b = hb & 3, h = hb >> 2;
            if (tid < 64) {
                float qv = bq_l[h * 64 + tid];
#pragma unroll
                for (int j = 0; j < 8; ++j)
                    qv += ld_coh(&qkvp[(size_t)((j * HH + h) * BB + b) * 64 + tid]);
                qs[tid] = qv;
            } else if (tid < 128 && c == 0) {
                int t2 = tid - 64;
                float kn = 0.f;
#pragma unroll
                for (int j = 0; j < 8; ++j)
                    kn += ld_coh(&qkvp[(size_t)(((8 + j) * HH + h) * BB + b) * 64 + t2]);
                knS[t2] = kn;
                nk_l[((size_t)(b * HH + h) * 64 + t2) * KVLEN + HIST] = kn;
            } else if (tid < 192 && c == 0) {
                int t2 = tid - 128;
                float vn = bv_l[h * 64 + t2];
#pragma unroll
                for (int j = 0; j < 8; ++j)
                    vn += ld_coh(&qkvp[(size_t)(((16 + j) * HH + h) * BB + b) * 64 + t2]);
                vnS[t2] = vn;
                nv_l[(size_t)(b * HH + h) * KVLEN * 64 + (size_t)HIST * 64 + t2] = vn;
            }
            __syncthreads();
            // K phase
            int clK = tid & 31, gK = tid >> 5;
            int jb = c * 128 + clK * 4;
            const float* kb = kc_l + (size_t)(b * HH + h) * 64 * HIST;
            float* nkb = nk_l + (size_t)(b * HH + h) * 64 * KVLEN;
            float ax = 0, ay = 0, az = 0, aw = 0;
#pragma unroll
            for (int it = 0; it < 8; ++it) {
                int dh = gK * 8 + it;
                float4 k4 = *(const float4*)(kb + (size_t)dh * HIST + jb);
                float* nr = nkb + (size_t)dh * KVLEN + jb;
                nr[0] = k4.x; nr[1] = k4.y; nr[2] = k4.z; nr[3] = k4.w;
                float qd = qs[dh];
                ax += qd * k4.x; ay += qd * k4.y; az += qd * k4.z; aw += qd * k4.w;
            }
            sc8[gK * 128 + clK * 4 + 0] = ax; sc8[gK * 128 + clK * 4 + 1] = ay;
            sc8[gK * 128 + clK * 4 + 2] = az; sc8[gK * 128 + clK * 4 + 3] = aw;
            __syncthreads();
            float s = 0.f;
            if (tid < 128) {
#pragma unroll
                for (int g = 0; g < 8; ++g) s += sc8[g * 128 + tid];
                int j = c * 128 + tid;
                if (j != 0) s += -128.0f * flag;
            }
            if (c == 0 && tid < 64) {
                float pp = qs[tid] * knS[tid];
#pragma unroll
                for (int o = 32; o; o >>= 1) pp += __shfl_xor(pp, o, 64);
                if (tid == 0) snS[0] = pp + (-128.0f * flag);
            }
            if (tid < 128) redA[tid] = s;
            __syncthreads();
            for (int st = 64; st; st >>= 1) {
                if (tid < st) redA[tid] = fmaxf(redA[tid], redA[tid + st]);
                __syncthreads();
            }
            float m = redA[0];
            if (c == 0) m = fmaxf(m, snS[0]);
            __syncthreads();
            float pp = 0.f;
            if (tid < 128) { pp = expf(s - m); parr[tid] = pp; redA[tid] = pp; }
            __syncthreads();
            for (int st = 64; st; st >>= 1) {
                if (tid < st) redA[tid] += redA[tid + st];
                __syncthreads();
            }
            float ssum = redA[0];
            float en = (c == 0) ? expf(snS[0] - m) : 0.0f;
            // V phase
            int clV = tid & 15, rg = tid >> 4;
            const float* vb = vc_l + (size_t)(b * HH + h) * HIST * 64;
            float* nvb = nv_l + (size_t)(b * HH + h) * KVLEN * 64;
            float vx = 0, vy = 0, vz = 0, vw = 0;
#pragma unroll
            for (int it = 0; it < 8; ++it) {
                int i = rg * 8 + it;
                size_t jj = (size_t)(c * 128 + i);
                float4 v4 = *(const float4*)(vb + jj * 64 + clV * 4);
                *(float4*)(nvb + jj * 64 + clV * 4) = v4;
                float pw = parr[i];
                vx += pw * v4.x; vy += pw * v4.y; vz += pw * v4.z; vw += pw * v4.w;
            }
            pvred[rg * 64 + clV * 4 + 0] = vx; pvred[rg * 64 + clV * 4 + 1] = vy;
            pvred[rg * 64 + clV * 4 + 2] = vz; pvred[rg * 64 + clV * 4 + 3] = vw;
            __syncthreads();
            float* st_ = selfS + (size_t)((b * HH + h) * 8 + c) * 66;
            if (tid == 0) {
                st_coh(&st_[0], m); st_coh(&st_[1], ssum + en);
            }
            if (tid < 64) {
                float pv = 0.f;
#pragma unroll
                for (int rgi = 0; rgi < 16; ++rgi) pv += pvred[rgi * 64 + tid];
                if (c == 0) pv += en * vnS[tid];
                st_coh(&st_[2 + tid], pv);
            }
            __syncthreads();
        }
        gsync(p.bar, r);

        // ---- P3: fc out-proj, 320 units = rc*20+cc, rows=80, merge selfS(8) ----
        for (int u = bid; u < 320; u += G) {
            int cc = u % 20, rcx = u / 20, row0 = rcx * 80;
            for (int i = tid; i < 320; i += 256) {
                int b = i / 80, rr = i % 80, gr = row0 + rr, hh = gr >> 6, dh = gr & 63;
                const float* st = selfS + (size_t)((b * HH + hh) * 8) * 66;
                float M = ld_coh(&st[0]);
#pragma unroll
                for (int ci = 1; ci < 8; ++ci) M = fmaxf(M, ld_coh(&st[ci * 66]));
                float den = 0.f, num = 0.f;
#pragma unroll
                for (int ci = 0; ci < 8; ++ci) {
                    float e = expf(ld_coh(&st[ci * 66]) - M);
                    den += e * ld_coh(&st[ci * 66 + 1]);
                    num += e * ld_coh(&st[ci * 66 + 2 + dh]);
                }
                am[b * 80 + rr] = num / den;
            }
            __syncthreads();
            gemv_core(fcw_l + (size_t)row0 * DD + cc * 64, DD, 80, am, red,
                      fcP + (size_t)(rcx * BB) * DD, DD, cc * 64);
            __syncthreads();
        }
        gsync(p.bar, r);

        // ---- P4: LN1 ----
        if (bid < BB) ln_micro<16>(bid, x, fcb_l, fcP, p.cnw + l * DD, p.cnb + l * DD, xn, sm);
        gsync(p.bar, r);

        // ---- P5: cross Q, 160 units = h*8+rc, rows=160 ----
        for (int u = bid; u < 160; u += G) {
            int rc = u & 7, h = u >> 3;
            const float* W = cwq_l + (size_t)h * 81920 + (size_t)rc * 160 * 64;
            for (int i = tid; i < 640; i += 256)
                am[i] = ld_coh(&xn[(i / 160) * DD + rc * 160 + (i % 160)]);
            __syncthreads();
            gemv_core(W, 64, 160, am, red,
                      qkvp + (size_t)(rc * HH + h) * BB * 64, 64, 0);
            __syncthreads();
        }
        gsync(p.bar, r);

        // ---- P6: cross-attention, 320 units = ((h*4+b)*4)+c, chunk=128 ----
        for (int u = bid; u < 320; u += G) {
            int c = u & 3, hb = u >> 2, b = hb & 3, h = hb >> 2;
            if (tid < 64) {
                float qv = cbq_l[h * 64 + tid];
#pragma unroll
                for (int j = 0; j < 8; ++j)
                    qv += ld_coh(&qkvp[(size_t)((j * HH + h) * BB + b) * 64 + tid]);
                qs[tid] = qv;
            }
            __syncthreads();
            int clK = tid & 31, gK = tid >> 5;
            int jb = c * 128 + clK * 4;
            const float* kb = ck_l + (size_t)(b * HH + h) * 64 * TENC;
            float ax = 0, ay = 0, az = 0, aw = 0;
#pragma unroll
            for (int it = 0; it < 8; ++it) {
                int dh = gK * 8 + it;
                float4 k4 = *(const float4*)(kb + (size_t)dh * TENC + jb);
                float qd = qs[dh];
                ax += qd * k4.x; ay += qd * k4.y; az += qd * k4.z; aw += qd * k4.w;
            }
            sc8[gK * 128 + clK * 4 + 0] = ax; sc8[gK * 128 + clK * 4 + 1] = ay;
            sc8[gK * 128 + clK * 4 + 2] = az; sc8[gK * 128 + clK * 4 + 3] = aw;
            __syncthreads();
            float s = 0.f;
            if (tid < 128) {
#pragma unroll
                for (int g = 0; g < 8; ++g) s += sc8[g * 128 + tid];
            }
            if (tid < 128) redA[tid] = s;
            __syncthreads();
            for (int st = 64; st; st >>= 1) {
                if (tid < st) redA[tid] = fmaxf(redA[tid], redA[tid + st]);
                __syncthreads();
            }
            float m = redA[0];
            __syncthreads();
            float pp = 0.f;
            if (tid < 128) { pp = expf(s - m); parr[tid] = pp; redA[tid] = pp; }
            __syncthreads();
            for (int st = 64; st; st >>= 1) {
                if (tid < st) redA[tid] += redA[tid + st];
                __syncthreads();
            }
            float ssum = redA[0];
            int clV = tid & 15, rg = tid >> 4;
            const float* vb = cv_l + (size_t)(b * HH + h) * TENC * 64;
            float vx = 0, vy = 0, vz = 0, vw = 0;
#pragma unroll
            for (int it = 0; it < 8; ++it) {
                int i = rg * 8 + it;
                size_t jj = (size_t)(c * 128 + i);
                float4 v4 = *(const float4*)(vb + jj * 64 + clV * 4);
                float pw = parr[i];
                vx += pw * v4.x; vy += pw * v4.y; vz += pw * v4.z; vw += pw * v4.w;
            }
            pvred[rg * 64 + clV * 4 + 0] = vx; pvred[rg * 64 + clV * 4 + 1] = vy;
            pvred[rg * 64 + clV * 4 + 2] = vz; pvred[rg * 64 + clV * 4 + 3] = vw;
            __syncthreads();
            float* st_ = crossS + (size_t)((b * HH + h) * 4 + c) * 66;
            if (tid == 0) { st_coh(&st_[0], m); st_coh(&st_[1], ssum); }
            if (tid < 64) {
                float pv = 0.f;
#pragma unroll
                for (int rgi = 0; rgi < 16; ++rgi) pv += pvred[rgi * 64 + tid];
                st_coh(&st_[2 + tid], pv);
            }
            __syncthreads();
        }
        gsync(p.bar, r);

        // ---- P7: cfc out-proj, 320 units, merge crossS(4) ----
        for (int u = bid; u < 320; u += G) {
            int cc = u % 20, rcx = u / 20, row0 = rcx * 80;
            for (int i = tid; i < 320; i += 256) {
                int b = i / 80, rr = i % 80, gr = row0 + rr, hh = gr >> 6, dh = gr & 63;
                const float* st = crossS + (size_t)((b * HH + hh) * 4) * 66;
                float M = ld_coh(&st[0]);
#pragma unroll
                for (int ci = 1; ci < 4; ++ci) M = fmaxf(M, ld_coh(&st[ci * 66]));
                float den = 0.f, num = 0.f;
#pragma unroll
                for (int ci = 0; ci < 4; ++ci) {
                    float e = expf(ld_coh(&st[ci * 66]) - M);
                    den += e * ld_coh(&st[ci * 66 + 1]);
                    num += e * ld_coh(&st[ci * 66 + 2 + dh]);
                }
                am[b * 80 + rr] = num / den;
            }
            __syncthreads();
            gemv_core(cfcw_l + (size_t)row0 * DD + cc * 64, DD, 80, am, red,
                      cfcP + (size_t)(rcx * BB) * DD, DD, cc * 64);
            __syncthreads();
        }
        gsync(p.bar, r);

        // ---- P8: LN2 ----
        if (bid < BB) ln_micro<16>(bid, x, cfcb_l, cfcP, p.mnw + l * DD, p.mnb + l * DD, xn, sm);
        gsync(p.bar, r);

        // ---- P9: FFN1, 640 units = rc*80+cc, rows=160 ----
        for (int u = bid; u < 640; u += G) {
            int cc = u % 80, rcx = u / 80, row0 = rcx * 160;
            for (int i = tid; i < 640; i += 256)
                am[i] = ld_coh(&xn[(i / 160) * DD + row0 + (i % 160)]);
            __syncthreads();
            gemv_core(w1_l + (size_t)row0 * DFFN + cc * 64, DFFN, 160, am, red,
                      f1P + (size_t)(rcx * BB) * DFFN, DFFN, cc * 64);
            __syncthreads();
        }
        gsync(p.bar, r);

        // ---- P10: FFN2, 320 units = rc*20+cc, rows=320, relu-merge f1P(8) ----
        for (int u = bid; u < 320; u += G) {
            int cc = u % 20, rcx = u / 20, row0 = rcx * 320;
            for (int i = tid; i < 1280; i += 256) {
                int b = i / 320, rr = i % 320;
                float pv[8];
#pragma unroll
                for (int j = 0; j < 8; ++j)
                    pv[j] = ld_coh(&f1P[(size_t)(j * BB + b) * DFFN + row0 + rr]);
                float v = b1_l[row0 + rr];
#pragma unroll
                for (int j = 0; j < 8; ++j) v += pv[j];
                am[i] = fmaxf(v, 0.0f);
            }
            __syncthreads();
            gemv_core(w2_l + (size_t)row0 * DD + cc * 64, DD, 320, am, red,
                      ff2P + (size_t)(rcx * BB) * DD, DD, cc * 64);
            __syncthreads();
        }
        gsync(p.bar, r);

        // ---- P11: LN3 (next layer's snw/snb, or final lnow/lnob) ----
        if (bid < BB) {
            const float* nlw = (l < NLAYER - 1) ? p.snw + (l + 1) * DD : p.lnow;
            const float* nlb = (l < NLAYER - 1) ? p.snb + (l + 1) * DD : p.lnob;
            ln_micro<16>(bid, x, b2_l, ff2P, nlw, nlb, xn, sm);
        }
        gsync(p.bar, r);
    }

    // ---- P12: final projection, 500 units = rc*125+cc, rows=320 ----
    for (int u = bid; u < 500; u += G) {
        int cc = u % 125, rcx = u / 125, row0 = rcx * 320;
        for (int i = tid; i < 1280; i += 256)
            am[i] = ld_coh(&xn[(i / 320) * DD + row0 + (i % 320)]);
        __syncthreads();
        gemv_core(p.projw + (size_t)row0 * VV + cc * 64, VV, 320, am, red,
                  projP + (size_t)(rcx * BB) * VV, VV, cc * 64);
        __syncthreads();
    }
    gsync(p.bar, r);

    // ---- P13: logits finalize + kv scalar ----
    for (int u = bid; u < 125; u += G) {
        int b = tid >> 6, c = u * 64 + (tid & 63);
        float pv[4];
#pragma unroll
        for (int j = 0; j < 4; ++j) pv[j] = ld_coh(&projP[(size_t)(j * BB + b) * VV + c]);
        float v = p.projb[c];
#pragma unroll
        for (int j = 0; j < 4; ++j) v += pv[j];
        p.out[LG_OFF + (size_t)b * VV + c] = v;
    }
    if (bid == 0 && tid == 0) p.out[KV_IDX] = (float)(HIST + 1);
}

// ---------------- host ----------------
extern "C" void kernel_launch(void* const* d_in, const int* in_sizes, int n_in,
                              void* d_out, int out_size, void* d_ws, size_t ws_size,
                              hipStream_t stream) {
    Prm prm;
    prm.kc    = (const float*)d_in[0];
    prm.vc    = (const float*)d_in[1];
    prm.ck    = (const float*)d_in[2];
    prm.cv    = (const float*)d_in[3];
    prm.ids   = (const int*)d_in[4];
    prm.mflag = (const float*)d_in[7];
    prm.emb   = (const float*)d_in[8];
    prm.pe    = (const float*)d_in[9];
    prm.snw   = (const float*)d_in[10];
    prm.snb   = (const float*)d_in[11];
    prm.wq    = (const float*)d_in[12];
    prm.bq    = (const float*)d_in[13];
    prm.wk    = (const float*)d_in[14];
    prm.wv    = (const float*)d_in[15];
    prm.bv    = (const float*)d_in[16];
    prm.fcw   = (const float*)d_in[17];
    prm.fcb   = (const float*)d_in[18];
    prm.cnw   = (const float*)d_in[19];
    prm.cnb   = (const float*)d_in[20];
    prm.cwq   = (const float*)d_in[21];
    prm.cbq   = (const float*)d_in[22];
    prm.cfcw  = (const float*)d_in[23];
    prm.cfcb  = (const float*)d_in[24];
    prm.mnw   = (const float*)d_in[25];
    prm.mnb   = (const float*)d_in[26];
    prm.w1    = (const float*)d_in[27];
    prm.b1    = (const float*)d_in[28];
    prm.w2    = (const float*)d_in[29];
    prm.b2    = (const float*)d_in[30];
    prm.lnow  = (const float*)d_in[31];
    prm.lnob  = (const float*)d_in[32];
    prm.projw = (const float*)d_in[33];
    prm.projb = (const float*)d_in[34];
    prm.out   = (float*)d_out;
    prm.ws    = (float*)d_ws;
    prm.bar   = (unsigned*)d_ws;     // bar[0..4095]; data buffers start at ws+4096 floats

    // Query real co-residency and size the cooperative grid to fit (multiple of 32).
    int dev = 0;
    (void)hipGetDevice(&dev);
    int numCU = 0;
    if (hipDeviceGetAttribute(&numCU, hipDeviceAttributeMultiprocessorCount, dev) != hipSuccess || numCU <= 0)
        numCU = 256;
    int maxB = 0;
    if (hipOccupancyMaxActiveBlocksPerMultiprocessor(&maxB, reinterpret_cast<const void*>(mega), 256, 0) != hipSuccess || maxB <= 0)
        maxB = 1;
    int grid = maxB * numCU;
    if (grid > 640) grid = 640;   // max units in any phase; fewer arrivals per barrier
    grid &= ~31;
    if (grid < 32) grid = 32;

    bar_init<<<1, 256, 0, stream>>>(prm.bar);
    void* args[] = { &prm };
    hipError_t e = hipLaunchCooperativeKernel(reinterpret_cast<void*>(mega),
                                              dim3(grid), dim3(256), args, 0, stream);
    if (e != hipSuccess) {
        (void)hipGetLastError();   // clear error state
        // Fallback: plain launch. grid <= co-resident capacity, so the
        // persistent-block barrier still completes; spin is bounded anyway.
        hipLaunchKernelGGL(mega, dim3(grid), dim3(256), 0, stream, prm);
    }
}